// Round 1
// baseline (8672.213 us; speedup 1.0000x reference)
//
#include <hip/hip_runtime.h>
#include <math.h>

#define TTOK 8192   // B*S
#define DIMD 512
#define NHEAD 8
#define DHEAD 64
#define SEQ 2048
#define NEXP 8
#define NFF 2048
#define NLAYER 4

typedef __attribute__((ext_vector_type(8))) short short8v;   // 8 bf16 (4 VGPRs)
typedef __attribute__((ext_vector_type(4))) float f32x4;     // MFMA 16x16 accum

__device__ __forceinline__ float bf2f(unsigned short h) {
  union { unsigned u; float f; } c; c.u = ((unsigned)h) << 16; return c.f;
}
// split fp32 into truncated-bf16 hi + bf16(lo) ; a ~= hi + lo with ~2^-17 rel err
__device__ __forceinline__ void splitf(float v, unsigned short& hi, unsigned short& lo) {
  union { float f; unsigned u; } a; a.f = v;
  hi = (unsigned short)(a.u >> 16);
  union { unsigned u; float f; } b; b.u = a.u & 0xFFFF0000u;
  union { float f; unsigned u; } c; c.f = v - b.f;   // exact
  lo = (unsigned short)(c.u >> 16);
}

// ---------------- embedding + positional encoding -> bf16 hi/lo planes ----------------
__global__ __launch_bounds__(256) void embed_kernel(
    const int* __restrict__ tokens, const float* __restrict__ emb,
    unsigned short* __restrict__ Xh, unsigned short* __restrict__ Xl) {
  int idx = blockIdx.x * 256 + threadIdx.x;       // over TTOK*DIMD
  int t = idx >> 9;
  int d = idx & 511;
  int s = t & (SEQ - 1);
  int tok = tokens[t];
  float j2 = (float)((d >> 1) << 1);
  float freq = expf(-j2 * (9.210340371976184f / 512.0f));
  float angle = (float)s * freq;
  float pe = (d & 1) ? cosf(angle) : sinf(angle);
  float v = emb[tok * DIMD + d] * 22.627416997969522f + pe;
  unsigned short hu, lu; splitf(v, hu, lu);
  Xh[idx] = hu; Xl[idx] = lu;
}

// ---------------- weight converter: W[K=512][N=512] fp32 -> MFMA fragment image ------
// img layout per expert: [kt 0..15][nf 0..31][lane 0..63][8 bf16]
// slot (kt,nf,lane): element j = W[kt*32 + (lane>>4)*8 + j][nf*16 + (lane&15)]
__global__ __launch_bounds__(256) void conv_w_kernel(
    const float* __restrict__ src, int ld, size_t eStride,
    unsigned short* __restrict__ hi, unsigned short* __restrict__ lo) {
  int e = blockIdx.z;
  int s = blockIdx.x * 256 + threadIdx.x;         // slot within expert (0..32767)
  int kt = s >> 11;
  int rem = s & 2047;
  int nf = rem >> 6;
  int l = rem & 63;
  int k = kt * 32 + ((l >> 4) << 3);
  int n = (nf << 4) + (l & 15);
  const float* p = src + (size_t)e * eStride + (size_t)k * ld + n;
  short8v h8, l8;
#pragma unroll
  for (int j = 0; j < 8; j++) {
    float v = p[(size_t)j * ld];
    unsigned short hu, lu; splitf(v, hu, lu);
    h8[j] = (short)hu; l8[j] = (short)lu;
  }
  size_t o = ((size_t)e * 32768 + s) * 8;
  *(short8v*)(hi + o) = h8;
  *(short8v*)(lo + o) = l8;
}

// ---------------- shared bf16x3 MFMA K-loop (K=512, BM=128, BN=64, BK=32) ------------
// 256 threads = 4 waves arranged 2x2; wave tile 64x32 = 4x2 fragments of 16x16.
// LDS fragment-linear slots (ushort idx = slot*8):
//   A_hi 0..511 | A_lo 512..1023 | B_hi 1024..1279 | B_lo 1280..1535   (24 KB)
__device__ __forceinline__ void mfma_loop(
    const unsigned short* __restrict__ Ah, const unsigned short* __restrict__ Al,
    size_t rowoff0, size_t rowoff1,
    const unsigned short* __restrict__ Bh, const unsigned short* __restrict__ Bl,
    size_t bbase, unsigned short* lds, int w, int l, int wr, int wc,
    f32x4 acc[4][2]) {
  const unsigned short* pBh = Bh + bbase;
  const unsigned short* pBl = Bl + bbase;
  short8v r0h, r1h, r0l, r1l, rbh, rbl;

#define LOADK(kt)                                               \
  r0h = *(const short8v*)(Ah + rowoff0 + (kt) * 32);            \
  r1h = *(const short8v*)(Ah + rowoff1 + (kt) * 32);            \
  r0l = *(const short8v*)(Al + rowoff0 + (kt) * 32);            \
  r1l = *(const short8v*)(Al + rowoff1 + (kt) * 32);            \
  rbh = *(const short8v*)(pBh + (size_t)(kt) * 16384);          \
  rbl = *(const short8v*)(pBl + (size_t)(kt) * 16384);

#define STOREK()                                                \
  *(short8v*)&lds[(w * 128 + l) * 8] = r0h;                     \
  *(short8v*)&lds[(w * 128 + 64 + l) * 8] = r1h;                \
  *(short8v*)&lds[(512 + w * 128 + l) * 8] = r0l;               \
  *(short8v*)&lds[(512 + w * 128 + 64 + l) * 8] = r1l;          \
  *(short8v*)&lds[(1024 + w * 64 + l) * 8] = rbh;               \
  *(short8v*)&lds[(1280 + w * 64 + l) * 8] = rbl;

#define COMPK()                                                                              \
  {                                                                                          \
    short8v BH0 = *(const short8v*)&lds[(1024 + (wc * 2 + 0) * 64 + l) * 8];                 \
    short8v BL0 = *(const short8v*)&lds[(1280 + (wc * 2 + 0) * 64 + l) * 8];                 \
    short8v BH1 = *(const short8v*)&lds[(1024 + (wc * 2 + 1) * 64 + l) * 8];                 \
    short8v BL1 = *(const short8v*)&lds[(1280 + (wc * 2 + 1) * 64 + l) * 8];                 \
    _Pragma("unroll")                                                                        \
    for (int mf = 0; mf < 4; mf++) {                                                         \
      short8v AH = *(const short8v*)&lds[(((wr * 4 + mf) * 64) + l) * 8];                    \
      short8v AL2 = *(const short8v*)&lds[((512 + (wr * 4 + mf) * 64) + l) * 8];             \
      acc[mf][0] = __builtin_amdgcn_mfma_f32_16x16x32_bf16(AH, BH0, acc[mf][0], 0, 0, 0);    \
      acc[mf][0] = __builtin_amdgcn_mfma_f32_16x16x32_bf16(AH, BL0, acc[mf][0], 0, 0, 0);    \
      acc[mf][0] = __builtin_amdgcn_mfma_f32_16x16x32_bf16(AL2, BH0, acc[mf][0], 0, 0, 0);   \
      acc[mf][1] = __builtin_amdgcn_mfma_f32_16x16x32_bf16(AH, BH1, acc[mf][1], 0, 0, 0);    \
      acc[mf][1] = __builtin_amdgcn_mfma_f32_16x16x32_bf16(AH, BL1, acc[mf][1], 0, 0, 0);    \
      acc[mf][1] = __builtin_amdgcn_mfma_f32_16x16x32_bf16(AL2, BH1, acc[mf][1], 0, 0, 0);   \
    }                                                                                        \
  }

  LOADK(0);
  STOREK();
  __syncthreads();
  for (int kt = 0; kt < 15; kt++) {
    LOADK(kt + 1);       // next tile loads in flight while we compute current
    COMPK();
    __syncthreads();
    STOREK();
    __syncthreads();
  }
  COMPK();
#undef LOADK
#undef STOREK
#undef COMPK
}

// ---------------- dense GEMM: C[8192,512] = A(hi/lo) @ Bimg + bias ----------------
__global__ __launch_bounds__(256, 2) void gemm_dense(
    const unsigned short* __restrict__ Ah, const unsigned short* __restrict__ Al,
    const unsigned short* __restrict__ Bh, const unsigned short* __restrict__ Bl,
    const float* __restrict__ bias, float* __restrict__ C) {
  __shared__ unsigned short lds[12288];
  int t = threadIdx.x;
  int w = t >> 6, l = t & 63;
  int wr = w >> 1, wc = w & 1;
  int m0 = blockIdx.x * 128;
  int n0 = blockIdx.y * 64;
  f32x4 acc[4][2];
#pragma unroll
  for (int mf = 0; mf < 4; mf++)
#pragma unroll
    for (int nf = 0; nf < 2; nf++) acc[mf][nf] = {0.f, 0.f, 0.f, 0.f};
  int kb = (l >> 4) << 3;
  size_t rowoff0 = (size_t)(m0 + (w * 2 + 0) * 16 + (l & 15)) * 512 + kb;
  size_t rowoff1 = (size_t)(m0 + (w * 2 + 1) * 16 + (l & 15)) * 512 + kb;
  size_t bbase = (size_t)(((n0 >> 4) + w) * 64 + l) * 8;
  mfma_loop(Ah, Al, rowoff0, rowoff1, Bh, Bl, bbase, lds, w, l, wr, wc, acc);
#pragma unroll
  for (int nf = 0; nf < 2; nf++) {
    int col = n0 + (wc * 2 + nf) * 16 + (l & 15);
    float bv = bias[col];
#pragma unroll
    for (int mf = 0; mf < 4; mf++) {
      int row = m0 + (wr * 4 + mf) * 16 + ((l >> 4) << 2);
#pragma unroll
      for (int i = 0; i < 4; i++)
        C[(size_t)(row + i) * 512 + col] = acc[mf][nf][i] + bv;
    }
  }
}

// ---------------- FFN1: H[enc] = relu(OUT1[token]@W1c + b1) -> bf16 hi/lo ----------------
__global__ __launch_bounds__(256, 2) void ffn1_mfma(
    const unsigned short* __restrict__ Ah, const unsigned short* __restrict__ Al,
    const unsigned short* __restrict__ Bh, const unsigned short* __restrict__ Bl,
    const float* __restrict__ b1c,
    unsigned short* __restrict__ Hh, unsigned short* __restrict__ Hl,
    const int* __restrict__ lists, const int* __restrict__ counts) {
  int e = blockIdx.z;
  int cnt = counts[e];
  int m0 = blockIdx.x * 128;
  if (m0 >= cnt) return;
  __shared__ unsigned short lds[12288];
  __shared__ int rowenc[128];
  int t = threadIdx.x;
  if (t < 128) {
    int r = m0 + t;
    rowenc[t] = (r < cnt) ? lists[e * TTOK + r] : -1;
  }
  __syncthreads();
  int w = t >> 6, l = t & 63;
  int wr = w >> 1, wc = w & 1;
  int n0 = blockIdx.y * 64;
  f32x4 acc[4][2];
#pragma unroll
  for (int mf = 0; mf < 4; mf++)
#pragma unroll
    for (int nf = 0; nf < 2; nf++) acc[mf][nf] = {0.f, 0.f, 0.f, 0.f};
  int kb = (l >> 4) << 3;
  int enc0 = rowenc[(w * 2 + 0) * 16 + (l & 15)];
  int enc1 = rowenc[(w * 2 + 1) * 16 + (l & 15)];
  size_t rowoff0 = (size_t)(enc0 >= 0 ? (enc0 >> 1) : 0) * 512 + kb;
  size_t rowoff1 = (size_t)(enc1 >= 0 ? (enc1 >> 1) : 0) * 512 + kb;
  size_t bbase = (size_t)e * 262144 + (size_t)(((n0 >> 4) + w) * 64 + l) * 8;
  mfma_loop(Ah, Al, rowoff0, rowoff1, Bh, Bl, bbase, lds, w, l, wr, wc, acc);
#pragma unroll
  for (int nf = 0; nf < 2; nf++) {
    int col = n0 + (wc * 2 + nf) * 16 + (l & 15);
    float bv = b1c[e * NFF + col];
#pragma unroll
    for (int mf = 0; mf < 4; mf++) {
      int lrow = (wr * 4 + mf) * 16 + ((l >> 4) << 2);
#pragma unroll
      for (int i = 0; i < 4; i++) {
        int enc = rowenc[lrow + i];
        if (enc >= 0) {
          float v = fmaxf(acc[mf][nf][i] + bv, 0.f);
          unsigned short hu, lu; splitf(v, hu, lu);
          Hh[(size_t)enc * 512 + col] = hu;
          Hl[(size_t)enc * 512 + col] = lu;
        }
      }
    }
  }
}

// ---------------- FFN2: Oslot[enc] (c==0? =bias+ : +=) H[enc] @ W2c ----------------
__global__ __launch_bounds__(256, 2) void ffn2_mfma(
    const unsigned short* __restrict__ Ah, const unsigned short* __restrict__ Al,
    const unsigned short* __restrict__ Bh, const unsigned short* __restrict__ Bl,
    const float* __restrict__ b2i,
    float* __restrict__ OS0, float* __restrict__ OS1,
    const int* __restrict__ lists, const int* __restrict__ counts, int c) {
  int e = blockIdx.z;
  int cnt = counts[e];
  int m0 = blockIdx.x * 128;
  if (m0 >= cnt) return;
  __shared__ unsigned short lds[12288];
  __shared__ int rowenc[128];
  int t = threadIdx.x;
  if (t < 128) {
    int r = m0 + t;
    rowenc[t] = (r < cnt) ? lists[e * TTOK + r] : -1;
  }
  __syncthreads();
  int w = t >> 6, l = t & 63;
  int wr = w >> 1, wc = w & 1;
  int n0 = blockIdx.y * 64;
  f32x4 acc[4][2];
#pragma unroll
  for (int mf = 0; mf < 4; mf++)
#pragma unroll
    for (int nf = 0; nf < 2; nf++) acc[mf][nf] = {0.f, 0.f, 0.f, 0.f};
  int kb = (l >> 4) << 3;
  int enc0 = rowenc[(w * 2 + 0) * 16 + (l & 15)];
  int enc1 = rowenc[(w * 2 + 1) * 16 + (l & 15)];
  size_t rowoff0 = (size_t)(enc0 >= 0 ? enc0 : 0) * 512 + kb;
  size_t rowoff1 = (size_t)(enc1 >= 0 ? enc1 : 0) * 512 + kb;
  size_t bbase = (size_t)e * 262144 + (size_t)(((n0 >> 4) + w) * 64 + l) * 8;
  mfma_loop(Ah, Al, rowoff0, rowoff1, Bh, Bl, bbase, lds, w, l, wr, wc, acc);
#pragma unroll
  for (int nf = 0; nf < 2; nf++) {
    int col = n0 + (wc * 2 + nf) * 16 + (l & 15);
    float bv = b2i[e * DIMD + col];
#pragma unroll
    for (int mf = 0; mf < 4; mf++) {
      int lrow = (wr * 4 + mf) * 16 + ((l >> 4) << 2);
#pragma unroll
      for (int i = 0; i < 4; i++) {
        int enc = rowenc[lrow + i];
        if (enc >= 0) {
          float* dst = (enc < 8192 ? OS0 + (size_t)enc * 512
                                   : OS1 + (size_t)(enc - 8192) * 512) + col;
          float v = acc[mf][nf][i];
          if (c == 0) v += bv; else v += *dst;
          *dst = v;
        }
      }
    }
  }
}

// ---------------- flash-style attention (fp32, online softmax) -> bf16 hi/lo ----------
__global__ __launch_bounds__(256) void attn_kernel(
    const float* __restrict__ q, const float* __restrict__ k,
    const float* __restrict__ v,
    unsigned short* __restrict__ ATTh, unsigned short* __restrict__ ATTl) {
  __shared__ float Ks[64][64];
  __shared__ float Vs[64][64];
  int t = threadIdx.x;
  int part = t & 3;
  int qr = t >> 2;
  int qtile = blockIdx.x;
  int bh = blockIdx.y;
  int b = bh >> 3, h = bh & 7;
  const float* qbase = q + (size_t)b * SEQ * DIMD + h * DHEAD;
  const float* kbase = k + (size_t)b * SEQ * DIMD + h * DHEAD;
  const float* vbase = v + (size_t)b * SEQ * DIMD + h * DHEAD;
  int qrow = qtile * 64 + qr;

  float qreg[16];
#pragma unroll
  for (int j = 0; j < 16; j += 4) {
    float4 tmp = *(const float4*)(qbase + (size_t)qrow * DIMD + part * 16 + j);
    qreg[j] = tmp.x; qreg[j + 1] = tmp.y; qreg[j + 2] = tmp.z; qreg[j + 3] = tmp.w;
  }
  float m = -1e30f, l = 0.0f;
  float O[16];
#pragma unroll
  for (int j = 0; j < 16; j++) O[j] = 0.0f;

  for (int kt = 0; kt < SEQ / 64; kt++) {
#pragma unroll
    for (int i = 0; i < 4; i++) {
      int idx4 = t + i * 256;
      int r = idx4 >> 4;
      int c4 = idx4 & 15;
      *(float4*)(&Ks[r][c4 << 2]) =
          *(const float4*)(kbase + (size_t)(kt * 64 + r) * DIMD + (c4 << 2));
      *(float4*)(&Vs[r][c4 << 2]) =
          *(const float4*)(vbase + (size_t)(kt * 64 + r) * DIMD + (c4 << 2));
    }
    __syncthreads();
    for (int kk = 0; kk < 64; kk++) {
      float p = 0.0f;
#pragma unroll
      for (int j = 0; j < 16; j++) p += qreg[j] * Ks[kk][part * 16 + j];
      p += __shfl_xor(p, 1);
      p += __shfl_xor(p, 2);
      float s = p * 0.125f;
      float mnew = fmaxf(m, s);
      float alpha = __expf(m - mnew);
      float pr = __expf(s - mnew);
      l = l * alpha + pr;
#pragma unroll
      for (int j = 0; j < 16; j++)
        O[j] = O[j] * alpha + pr * Vs[kk][part * 16 + j];
      m = mnew;
    }
    __syncthreads();
  }
  float inv = 1.0f / l;
  unsigned short* oh = ATTh + (size_t)b * SEQ * DIMD + h * DHEAD + (size_t)qrow * DIMD + part * 16;
  unsigned short* ol = ATTl + (size_t)b * SEQ * DIMD + h * DHEAD + (size_t)qrow * DIMD + part * 16;
#pragma unroll
  for (int j0 = 0; j0 < 16; j0 += 8) {
    short8v h8, l8v;
#pragma unroll
    for (int j = 0; j < 8; j++) {
      unsigned short hu, lu; splitf(O[j0 + j] * inv, hu, lu);
      h8[j] = (short)hu; l8v[j] = (short)lu;
    }
    *(short8v*)(oh + j0) = h8;
    *(short8v*)(ol + j0) = l8v;
  }
}

// ---------------- LayerNorm((Xh+Xl) + p) * g + be -> bf16 hi/lo ----------------
__global__ __launch_bounds__(256) void ln_add_kernel(
    const unsigned short* __restrict__ Xh, const unsigned short* __restrict__ Xl,
    const float* __restrict__ p,
    const float* __restrict__ g, const float* __restrict__ be,
    unsigned short* __restrict__ outH, unsigned short* __restrict__ outL) {
  int wave = threadIdx.x >> 6;
  int lane = threadIdx.x & 63;
  int token = blockIdx.x * 4 + wave;
  short8v h8 = *(const short8v*)(Xh + (size_t)token * 512 + lane * 8);
  short8v l8 = *(const short8v*)(Xl + (size_t)token * 512 + lane * 8);
  const float* pr = p + (size_t)token * 512 + lane * 8;
  float pv[8];
  *(float4*)(&pv[0]) = *(const float4*)(pr);
  *(float4*)(&pv[4]) = *(const float4*)(pr + 4);
  float vals[8];
  float sum = 0.0f;
#pragma unroll
  for (int j = 0; j < 8; j++) {
    float v = bf2f((unsigned short)h8[j]) + bf2f((unsigned short)l8[j]) + pv[j];
    vals[j] = v; sum += v;
  }
#pragma unroll
  for (int off = 32; off; off >>= 1) sum += __shfl_xor(sum, off);
  float mu = sum * (1.0f / 512.0f);
  float sq = 0.0f;
#pragma unroll
  for (int j = 0; j < 8; j++) { vals[j] -= mu; sq += vals[j] * vals[j]; }
#pragma unroll
  for (int off = 32; off; off >>= 1) sq += __shfl_xor(sq, off);
  float rs = rsqrtf(sq * (1.0f / 512.0f) + 1e-6f);
  short8v oh, ol;
#pragma unroll
  for (int j = 0; j < 8; j++) {
    int d = lane * 8 + j;
    float y = vals[j] * rs * g[d] + be[d];
    unsigned short hu, lu; splitf(y, hu, lu);
    oh[j] = (short)hu; ol[j] = (short)lu;
  }
  *(short8v*)(outH + (size_t)token * 512 + lane * 8) = oh;
  *(short8v*)(outL + (size_t)token * 512 + lane * 8) = ol;
}

// ---------------- LayerNorm(OUT1 + g0*o0 + g1*o1) -> fp32 (last) or bf16 hi/lo ----------
__global__ __launch_bounds__(256) void ln_moe_kernel(
    const unsigned short* __restrict__ O1h, const unsigned short* __restrict__ O1l,
    const float* __restrict__ OS0, const float* __restrict__ OS1,
    const float* __restrict__ gates, const float* __restrict__ g,
    const float* __restrict__ be, float* __restrict__ outF,
    unsigned short* __restrict__ outH, unsigned short* __restrict__ outL) {
  int wave = threadIdx.x >> 6;
  int lane = threadIdx.x & 63;
  int token = blockIdx.x * 4 + wave;
  short8v h8 = *(const short8v*)(O1h + (size_t)token * 512 + lane * 8);
  short8v l8 = *(const short8v*)(O1l + (size_t)token * 512 + lane * 8);
  const float* ob = (token < 4096) ? (OS0 + (size_t)token * 1024)
                                   : (OS1 + ((size_t)token - 4096) * 1024);
  const float* o0 = ob + lane * 8;
  const float* o1 = ob + 512 + lane * 8;
  float gate0 = gates[token * 2], gate1 = gates[token * 2 + 1];
  float a0[8], a1[8];
  *(float4*)(&a0[0]) = *(const float4*)(o0);
  *(float4*)(&a0[4]) = *(const float4*)(o0 + 4);
  *(float4*)(&a1[0]) = *(const float4*)(o1);
  *(float4*)(&a1[4]) = *(const float4*)(o1 + 4);
  float vals[8];
  float sum = 0.0f;
#pragma unroll
  for (int j = 0; j < 8; j++) {
    float v = bf2f((unsigned short)h8[j]) + bf2f((unsigned short)l8[j]) +
              gate0 * a0[j] + gate1 * a1[j];
    vals[j] = v; sum += v;
  }
#pragma unroll
  for (int off = 32; off; off >>= 1) sum += __shfl_xor(sum, off);
  float mu = sum * (1.0f / 512.0f);
  float sq = 0.0f;
#pragma unroll
  for (int j = 0; j < 8; j++) { vals[j] -= mu; sq += vals[j] * vals[j]; }
#pragma unroll
  for (int off = 32; off; off >>= 1) sq += __shfl_xor(sq, off);
  float rs = rsqrtf(sq * (1.0f / 512.0f) + 1e-6f);
  if (outF) {
#pragma unroll
    for (int j = 0; j < 8; j++) {
      int d = lane * 8 + j;
      outF[(size_t)token * 512 + d] = vals[j] * rs * g[d] + be[d];
    }
  } else {
    short8v oh, ol;
#pragma unroll
    for (int j = 0; j < 8; j++) {
      int d = lane * 8 + j;
      float y = vals[j] * rs * g[d] + be[d];
      unsigned short hu, lu; splitf(y, hu, lu);
      oh[j] = (short)hu; ol[j] = (short)lu;
    }
    *(short8v*)(outH + (size_t)token * 512 + lane * 8) = oh;
    *(short8v*)(outL + (size_t)token * 512 + lane * 8) = ol;
  }
}

// ---------------- MoE routing: softmax top-2 + bucket by expert ----------------
__global__ __launch_bounds__(256) void route_kernel(
    const unsigned short* __restrict__ Xh, const unsigned short* __restrict__ Xl,
    const float* __restrict__ Wg, const float* __restrict__ bg,
    float* __restrict__ gates, int* __restrict__ lists, int* __restrict__ counts) {
  int wave = threadIdx.x >> 6;
  int lane = threadIdx.x & 63;
  int token = blockIdx.x * 4 + wave;
  float acc[8];
#pragma unroll
  for (int e = 0; e < 8; e++) acc[e] = 0.0f;
  for (int it = 0; it < 8; it++) {
    int d = it * 64 + lane;
    float xv = bf2f(Xh[(size_t)token * 512 + d]) + bf2f(Xl[(size_t)token * 512 + d]);
    float4 w0 = *(const float4*)(Wg + d * 8);
    float4 w1 = *(const float4*)(Wg + d * 8 + 4);
    acc[0] += xv * w0.x; acc[1] += xv * w0.y;
    acc[2] += xv * w0.z; acc[3] += xv * w0.w;
    acc[4] += xv * w1.x; acc[5] += xv * w1.y;
    acc[6] += xv * w1.z; acc[7] += xv * w1.w;
  }
#pragma unroll
  for (int e = 0; e < 8; e++)
#pragma unroll
    for (int off = 32; off; off >>= 1) acc[e] += __shfl_xor(acc[e], off);
  if (lane == 0) {
    float lg[8];
    float mx = -1e30f;
#pragma unroll
    for (int e = 0; e < 8; e++) { lg[e] = acc[e] + bg[e]; mx = fmaxf(mx, lg[e]); }
#pragma unroll
    for (int e = 0; e < 8; e++) lg[e] = __expf(lg[e] - mx);
    int i0 = 0; float v0 = lg[0];
#pragma unroll
    for (int e = 1; e < 8; e++) if (lg[e] > v0) { v0 = lg[e]; i0 = e; }
    int i1 = -1; float v1 = -1.0f;
#pragma unroll
    for (int e = 0; e < 8; e++)
      if (e != i0 && lg[e] > v1) { v1 = lg[e]; i1 = e; }
    float inv = 1.0f / (v0 + v1);
    gates[token * 2] = v0 * inv;
    gates[token * 2 + 1] = v1 * inv;
    int p0 = atomicAdd(&counts[i0], 1);
    lists[i0 * TTOK + p0] = token * 2;
    int p1 = atomicAdd(&counts[i1], 1);
    lists[i1 * TTOK + p1] = token * 2 + 1;
  }
}

__global__ void zero_counts_kernel(int* counts) {
  if (threadIdx.x < NEXP) counts[threadIdx.x] = 0;
}

// ---------------- host orchestration ----------------
// Workspace layout (bytes, aliased by phase; total ~100.4 MB < 112.3 MB known-safe):
//  [0..16M)    Xh(8M)+Xl(8M)           | Hl (MoE)
//  [16..32M)   Q fp32                  | W1c_h/W1c_l/W2c_h/W2c_l images (4M each)
//  [32..48M)   Kb fp32                 | PROJ fp32 | Oslot rows 0..8191
//  [48..64M)   Vb fp32                 | OUT1h(8M)+OUT1l(8M)
//  [64..80M)   ATTh(8M)+ATTl(8M)       | Hh (MoE)
//  [80..84M)   Wq/Wk/Wv/Wo images (8 planes x 512KB)
//  [84..100M)  Oslot rows 8192..16383
//  [100M..)    GATES(64K) LISTS(256K) COUNTS
extern "C" void kernel_launch(void* const* d_in, const int* in_sizes, int n_in,
                              void* d_out, int out_size, void* d_ws, size_t ws_size,
                              hipStream_t stream) {
  (void)in_sizes; (void)n_in; (void)out_size; (void)ws_size;
  const int*   tokens = (const int*)d_in[0];
  const float* emb = (const float*)d_in[1];
  const float* Wq = (const float*)d_in[2];
  const float* bq = (const float*)d_in[3];
  const float* Wk = (const float*)d_in[4];
  const float* bk = (const float*)d_in[5];
  const float* Wv = (const float*)d_in[6];
  const float* bv = (const float*)d_in[7];
  const float* Wo = (const float*)d_in[8];
  const float* bo = (const float*)d_in[9];
  const float* Wg = (const float*)d_in[10];
  const float* bg = (const float*)d_in[11];
  const float* W1 = (const float*)d_in[12];
  const float* b1 = (const float*)d_in[13];
  const float* W2 = (const float*)d_in[14];
  const float* b2 = (const float*)d_in[15];
  const float* g1 = (const float*)d_in[16];
  const float* be1 = (const float*)d_in[17];
  const float* g2 = (const float*)d_in[18];
  const float* be2 = (const float*)d_in[19];

  char* base = (char*)d_ws;
  const size_t MB = 1024u * 1024u;
  unsigned short* Xh   = (unsigned short*)(base + 0 * MB);
  unsigned short* Xl   = (unsigned short*)(base + 8 * MB);
  unsigned short* Hl   = (unsigned short*)(base + 0 * MB);
  float*          Q    = (float*)(base + 16 * MB);
  unsigned short* W1h  = (unsigned short*)(base + 16 * MB);
  unsigned short* W1l  = (unsigned short*)(base + 20 * MB);
  unsigned short* W2h  = (unsigned short*)(base + 24 * MB);
  unsigned short* W2l  = (unsigned short*)(base + 28 * MB);
  float*          Kb   = (float*)(base + 32 * MB);
  float*          PROJ = (float*)(base + 32 * MB);
  float*          OS0  = (float*)(base + 32 * MB);
  float*          Vb   = (float*)(base + 48 * MB);
  unsigned short* O1h  = (unsigned short*)(base + 48 * MB);
  unsigned short* O1l  = (unsigned short*)(base + 56 * MB);
  unsigned short* ATTh = (unsigned short*)(base + 64 * MB);
  unsigned short* ATTl = (unsigned short*)(base + 72 * MB);
  unsigned short* Hh   = (unsigned short*)(base + 64 * MB);
  unsigned short* Wimg = (unsigned short*)(base + 80 * MB);
  float*          OS1  = (float*)(base + 84 * MB);
  float*          GATES = (float*)(base + 100 * MB);
  int*            LISTS = (int*)(base + 100 * MB + 65536);
  int*            COUNTS = (int*)(base + 100 * MB + 65536 + 262144);

  const size_t WPL = 262144;  // ushorts per 512x512 weight plane

  dim3 blk(256);
  embed_kernel<<<(TTOK * DIMD) / 256, blk, 0, stream>>>(tokens, emb, Xh, Xl);

  for (int i = 0; i < NLAYER; i++) {
    const float* wq = Wq + (size_t)i * DIMD * DIMD;
    const float* wk = Wk + (size_t)i * DIMD * DIMD;
    const float* wv = Wv + (size_t)i * DIMD * DIMD;
    const float* wo = Wo + (size_t)i * DIMD * DIMD;
    const float* bqi = bq + (size_t)i * DIMD;
    const float* bki = bk + (size_t)i * DIMD;
    const float* bvi = bv + (size_t)i * DIMD;
    const float* boi = bo + (size_t)i * DIMD;
    const float* wgi = Wg + (size_t)i * DIMD * NEXP;
    const float* bgi = bg + (size_t)i * NEXP;
    const float* w1i = W1 + (size_t)i * NEXP * DIMD * NFF;
    const float* b1i = b1 + (size_t)i * NEXP * NFF;
    const float* w2i = W2 + (size_t)i * NEXP * NFF * DIMD;
    const float* b2i = b2 + (size_t)i * NEXP * DIMD;
    const float* g1i = g1 + (size_t)i * DIMD;
    const float* be1i = be1 + (size_t)i * DIMD;
    const float* g2i = g2 + (size_t)i * DIMD;
    const float* be2i = be2 + (size_t)i * DIMD;

    conv_w_kernel<<<dim3(128, 1, 1), blk, 0, stream>>>(wq, 512, 0, Wimg + 0 * WPL, Wimg + 1 * WPL);
    conv_w_kernel<<<dim3(128, 1, 1), blk, 0, stream>>>(wk, 512, 0, Wimg + 2 * WPL, Wimg + 3 * WPL);
    conv_w_kernel<<<dim3(128, 1, 1), blk, 0, stream>>>(wv, 512, 0, Wimg + 4 * WPL, Wimg + 5 * WPL);
    conv_w_kernel<<<dim3(128, 1, 1), blk, 0, stream>>>(wo, 512, 0, Wimg + 6 * WPL, Wimg + 7 * WPL);

    dim3 gg(64, 8);
    gemm_dense<<<gg, blk, 0, stream>>>(Xh, Xl, Wimg + 0 * WPL, Wimg + 1 * WPL, bqi, Q);
    gemm_dense<<<gg, blk, 0, stream>>>(Xh, Xl, Wimg + 2 * WPL, Wimg + 3 * WPL, bki, Kb);
    gemm_dense<<<gg, blk, 0, stream>>>(Xh, Xl, Wimg + 4 * WPL, Wimg + 5 * WPL, bvi, Vb);
    attn_kernel<<<dim3(SEQ / 64, 32), blk, 0, stream>>>(Q, Kb, Vb, ATTh, ATTl);
    gemm_dense<<<gg, blk, 0, stream>>>(ATTh, ATTl, Wimg + 6 * WPL, Wimg + 7 * WPL, boi, PROJ);

    ln_add_kernel<<<TTOK / 4, blk, 0, stream>>>(Xh, Xl, PROJ, g1i, be1i, O1h, O1l);
    zero_counts_kernel<<<1, 64, 0, stream>>>(COUNTS);
    route_kernel<<<TTOK / 4, blk, 0, stream>>>(O1h, O1l, wgi, bgi, GATES, LISTS, COUNTS);

    for (int c = 0; c < 4; c++) {
      conv_w_kernel<<<dim3(128, 1, 8), blk, 0, stream>>>(
          w1i + c * 512, NFF, (size_t)DIMD * NFF, W1h, W1l);
      conv_w_kernel<<<dim3(128, 1, 8), blk, 0, stream>>>(
          w2i + (size_t)c * 512 * DIMD, DIMD, (size_t)NFF * DIMD, W2h, W2l);
      ffn1_mfma<<<dim3(64, 8, 8), blk, 0, stream>>>(
          O1h, O1l, W1h, W1l, b1i + c * 512, Hh, Hl, LISTS, COUNTS);
      ffn2_mfma<<<dim3(64, 8, 8), blk, 0, stream>>>(
          Hh, Hl, W2h, W2l, b2i, OS0, OS1, LISTS, COUNTS, c);
    }
    float* xout = (i == NLAYER - 1) ? (float*)d_out : nullptr;
    ln_moe_kernel<<<TTOK / 4, blk, 0, stream>>>(
        O1h, O1l, OS0, OS1, GATES, g2i, be2i, xout, Xh, Xl);
  }
}

// Round 4
// 5732.543 us; speedup vs baseline: 1.5128x; 1.5128x over previous
//
#include <hip/hip_runtime.h>
#include <math.h>

#define TTOK 8192   // B*S
#define DIMD 512
#define NHEAD 8
#define DHEAD 64
#define SEQ 2048
#define NEXP 8
#define NFF 2048
#define NLAYER 4

typedef __attribute__((ext_vector_type(8))) short short8v;   // 8 bf16 (4 VGPRs)
typedef __attribute__((ext_vector_type(4))) float f32x4;     // MFMA 16x16 accum

__device__ __forceinline__ float bf2f(unsigned short h) {
  union { unsigned u; float f; } c; c.u = ((unsigned)h) << 16; return c.f;
}
// split fp32 into truncated-bf16 hi + bf16(lo) ; a ~= hi + lo with ~2^-17 rel err
__device__ __forceinline__ void splitf(float v, unsigned short& hi, unsigned short& lo) {
  union { float f; unsigned u; } a; a.f = v;
  hi = (unsigned short)(a.u >> 16);
  union { unsigned u; float f; } b; b.u = a.u & 0xFFFF0000u;
  union { float f; unsigned u; } c; c.f = v - b.f;   // exact
  lo = (unsigned short)(c.u >> 16);
}

// ---------------- embedding + positional encoding -> bf16 hi/lo planes ----------------
__global__ __launch_bounds__(256) void embed_kernel(
    const int* __restrict__ tokens, const float* __restrict__ emb,
    unsigned short* __restrict__ Xh, unsigned short* __restrict__ Xl) {
  int idx = blockIdx.x * 256 + threadIdx.x;       // over TTOK*DIMD
  int t = idx >> 9;
  int d = idx & 511;
  int s = t & (SEQ - 1);
  int tok = tokens[t];
  float j2 = (float)((d >> 1) << 1);
  float freq = expf(-j2 * (9.210340371976184f / 512.0f));
  float angle = (float)s * freq;
  float pe = (d & 1) ? cosf(angle) : sinf(angle);
  float v = emb[tok * DIMD + d] * 22.627416997969522f + pe;
  unsigned short hu, lu; splitf(v, hu, lu);
  Xh[idx] = hu; Xl[idx] = lu;
}

// ---------------- weight converter: W[K=512][N=512] fp32 -> MFMA fragment image ------
// img layout per expert: [kt 0..15][nf 0..31][lane 0..63][8 bf16]
// slot (kt,nf,lane): element j = W[kt*32 + (lane>>4)*8 + j][nf*16 + (lane&15)]
__global__ __launch_bounds__(256) void conv_w_kernel(
    const float* __restrict__ src, int ld, size_t eStride,
    unsigned short* __restrict__ hi, unsigned short* __restrict__ lo) {
  int e = blockIdx.z;
  int s = blockIdx.x * 256 + threadIdx.x;         // slot within expert (0..32767)
  int kt = s >> 11;
  int rem = s & 2047;
  int nf = rem >> 6;
  int l = rem & 63;
  int k = kt * 32 + ((l >> 4) << 3);
  int n = (nf << 4) + (l & 15);
  const float* p = src + (size_t)e * eStride + (size_t)k * ld + n;
  short8v h8, l8;
#pragma unroll
  for (int j = 0; j < 8; j++) {
    float v = p[(size_t)j * ld];
    unsigned short hu, lu; splitf(v, hu, lu);
    h8[j] = (short)hu; l8[j] = (short)lu;
  }
  size_t o = ((size_t)e * 32768 + s) * 8;
  *(short8v*)(hi + o) = h8;
  *(short8v*)(lo + o) = l8;
}

// ---------------- shared bf16x3 MFMA K-loop (K=512, BM=128, BN=64, BK=32) ------------
__device__ __forceinline__ void mfma_loop(
    const unsigned short* __restrict__ Ah, const unsigned short* __restrict__ Al,
    size_t rowoff0, size_t rowoff1,
    const unsigned short* __restrict__ Bh, const unsigned short* __restrict__ Bl,
    size_t bbase, unsigned short* lds, int w, int l, int wr, int wc,
    f32x4 acc[4][2]) {
  const unsigned short* pBh = Bh + bbase;
  const unsigned short* pBl = Bl + bbase;
  short8v r0h, r1h, r0l, r1l, rbh, rbl;

#define LOADK(kt)                                               \
  r0h = *(const short8v*)(Ah + rowoff0 + (kt) * 32);            \
  r1h = *(const short8v*)(Ah + rowoff1 + (kt) * 32);            \
  r0l = *(const short8v*)(Al + rowoff0 + (kt) * 32);            \
  r1l = *(const short8v*)(Al + rowoff1 + (kt) * 32);            \
  rbh = *(const short8v*)(pBh + (size_t)(kt) * 16384);          \
  rbl = *(const short8v*)(pBl + (size_t)(kt) * 16384);

#define STOREK()                                                \
  *(short8v*)&lds[(w * 128 + l) * 8] = r0h;                     \
  *(short8v*)&lds[(w * 128 + 64 + l) * 8] = r1h;                \
  *(short8v*)&lds[(512 + w * 128 + l) * 8] = r0l;               \
  *(short8v*)&lds[(512 + w * 128 + 64 + l) * 8] = r1l;          \
  *(short8v*)&lds[(1024 + w * 64 + l) * 8] = rbh;               \
  *(short8v*)&lds[(1280 + w * 64 + l) * 8] = rbl;

#define COMPK()                                                                              \
  {                                                                                          \
    short8v BH0 = *(const short8v*)&lds[(1024 + (wc * 2 + 0) * 64 + l) * 8];                 \
    short8v BL0 = *(const short8v*)&lds[(1280 + (wc * 2 + 0) * 64 + l) * 8];                 \
    short8v BH1 = *(const short8v*)&lds[(1024 + (wc * 2 + 1) * 64 + l) * 8];                 \
    short8v BL1 = *(const short8v*)&lds[(1280 + (wc * 2 + 1) * 64 + l) * 8];                 \
    _Pragma("unroll")                                                                        \
    for (int mf = 0; mf < 4; mf++) {                                                         \
      short8v AH = *(const short8v*)&lds[(((wr * 4 + mf) * 64) + l) * 8];                    \
      short8v AL2 = *(const short8v*)&lds[((512 + (wr * 4 + mf) * 64) + l) * 8];             \
      acc[mf][0] = __builtin_amdgcn_mfma_f32_16x16x32_bf16(AH, BH0, acc[mf][0], 0, 0, 0);    \
      acc[mf][0] = __builtin_amdgcn_mfma_f32_16x16x32_bf16(AH, BL0, acc[mf][0], 0, 0, 0);    \
      acc[mf][0] = __builtin_amdgcn_mfma_f32_16x16x32_bf16(AL2, BH0, acc[mf][0], 0, 0, 0);   \
      acc[mf][1] = __builtin_amdgcn_mfma_f32_16x16x32_bf16(AH, BH1, acc[mf][1], 0, 0, 0);    \
      acc[mf][1] = __builtin_amdgcn_mfma_f32_16x16x32_bf16(AH, BL1, acc[mf][1], 0, 0, 0);    \
      acc[mf][1] = __builtin_amdgcn_mfma_f32_16x16x32_bf16(AL2, BH1, acc[mf][1], 0, 0, 0);   \
    }                                                                                        \
  }

  LOADK(0);
  STOREK();
  __syncthreads();
  for (int kt = 0; kt < 15; kt++) {
    LOADK(kt + 1);
    COMPK();
    __syncthreads();
    STOREK();
    __syncthreads();
  }
  COMPK();
#undef LOADK
#undef STOREK
#undef COMPK
}

// ---------------- dense GEMM, fp32 out: C = A(hi/lo) @ Bimg + bias ----------------
__global__ __launch_bounds__(256, 2) void gemm_dense(
    const unsigned short* __restrict__ Ah, const unsigned short* __restrict__ Al,
    const unsigned short* __restrict__ Bh, const unsigned short* __restrict__ Bl,
    const float* __restrict__ bias, float* __restrict__ C) {
  __shared__ unsigned short lds[12288];
  int t = threadIdx.x;
  int w = t >> 6, l = t & 63;
  int wr = w >> 1, wc = w & 1;
  int m0 = blockIdx.x * 128;
  int n0 = blockIdx.y * 64;
  f32x4 acc[4][2];
#pragma unroll
  for (int mf = 0; mf < 4; mf++)
#pragma unroll
    for (int nf = 0; nf < 2; nf++) acc[mf][nf] = {0.f, 0.f, 0.f, 0.f};
  int kb = (l >> 4) << 3;
  size_t rowoff0 = (size_t)(m0 + (w * 2 + 0) * 16 + (l & 15)) * 512 + kb;
  size_t rowoff1 = (size_t)(m0 + (w * 2 + 1) * 16 + (l & 15)) * 512 + kb;
  size_t bbase = (size_t)(((n0 >> 4) + w) * 64 + l) * 8;
  mfma_loop(Ah, Al, rowoff0, rowoff1, Bh, Bl, bbase, lds, w, l, wr, wc, acc);
#pragma unroll
  for (int nf = 0; nf < 2; nf++) {
    int col = n0 + (wc * 2 + nf) * 16 + (l & 15);
    float bv = bias[col];
#pragma unroll
    for (int mf = 0; mf < 4; mf++) {
      int row = m0 + (wr * 4 + mf) * 16 + ((l >> 4) << 2);
#pragma unroll
      for (int i = 0; i < 4; i++)
        C[(size_t)(row + i) * 512 + col] = acc[mf][nf][i] + bv;
    }
  }
}

// ---------------- dense GEMM, bf16 hi/lo out (for Q,K,V): (A@B + bias)*scale ----------
__global__ __launch_bounds__(256, 2) void gemm_dense_bf(
    const unsigned short* __restrict__ Ah, const unsigned short* __restrict__ Al,
    const unsigned short* __restrict__ Bh, const unsigned short* __restrict__ Bl,
    const float* __restrict__ bias,
    unsigned short* __restrict__ Ch, unsigned short* __restrict__ Cl, float scale) {
  __shared__ unsigned short lds[12288];
  int t = threadIdx.x;
  int w = t >> 6, l = t & 63;
  int wr = w >> 1, wc = w & 1;
  int m0 = blockIdx.x * 128;
  int n0 = blockIdx.y * 64;
  f32x4 acc[4][2];
#pragma unroll
  for (int mf = 0; mf < 4; mf++)
#pragma unroll
    for (int nf = 0; nf < 2; nf++) acc[mf][nf] = {0.f, 0.f, 0.f, 0.f};
  int kb = (l >> 4) << 3;
  size_t rowoff0 = (size_t)(m0 + (w * 2 + 0) * 16 + (l & 15)) * 512 + kb;
  size_t rowoff1 = (size_t)(m0 + (w * 2 + 1) * 16 + (l & 15)) * 512 + kb;
  size_t bbase = (size_t)(((n0 >> 4) + w) * 64 + l) * 8;
  mfma_loop(Ah, Al, rowoff0, rowoff1, Bh, Bl, bbase, lds, w, l, wr, wc, acc);
#pragma unroll
  for (int nf = 0; nf < 2; nf++) {
    int col = n0 + (wc * 2 + nf) * 16 + (l & 15);
    float bv = bias[col];
#pragma unroll
    for (int mf = 0; mf < 4; mf++) {
      int row = m0 + (wr * 4 + mf) * 16 + ((l >> 4) << 2);
#pragma unroll
      for (int i = 0; i < 4; i++) {
        float v = (acc[mf][nf][i] + bv) * scale;
        unsigned short hu, lu; splitf(v, hu, lu);
        Ch[(size_t)(row + i) * 512 + col] = hu;
        Cl[(size_t)(row + i) * 512 + col] = lu;
      }
    }
  }
}

// ---------------- MFMA flash attention (bf16x3 split, online softmax) ----------------
// 4 waves x 16 queries; 64-key tiles; K row-major LDS, V transposed LDS, both 72-pad.
__global__ __launch_bounds__(256, 2) void attn_mfma(
    const unsigned short* __restrict__ Qh, const unsigned short* __restrict__ Ql,
    const unsigned short* __restrict__ Kh, const unsigned short* __restrict__ Kl,
    const unsigned short* __restrict__ Vh, const unsigned short* __restrict__ Vl,
    unsigned short* __restrict__ ATTh, unsigned short* __restrict__ ATTl) {
  __shared__ __attribute__((aligned(16))) unsigned short KsH[64 * 72];
  __shared__ __attribute__((aligned(16))) unsigned short KsL[64 * 72];
  __shared__ __attribute__((aligned(16))) unsigned short VtH[64 * 72];
  __shared__ __attribute__((aligned(16))) unsigned short VtL[64 * 72];
  __shared__ __attribute__((aligned(16))) unsigned short Pb[4][2][16 * 72];
  int t = threadIdx.x;
  int w = t >> 6, l = t & 63;
  int lg = l >> 4, lr = l & 15;
  int qtile = blockIdx.x, bh = blockIdx.y;
  int b = bh >> 3, h = bh & 7;
  size_t hoff = (size_t)b * SEQ * DIMD + h * DHEAD;
  int q0 = qtile * 64 + w * 16;

  // Q fragments (A layout: row=lr, k=lg*8+j, two k-halves), Q pre-scaled by 1/8
  const unsigned short* qpH = Qh + hoff + (size_t)(q0 + lr) * DIMD + lg * 8;
  const unsigned short* qpL = Ql + hoff + (size_t)(q0 + lr) * DIMD + lg * 8;
  short8v qh0 = *(const short8v*)(qpH);
  short8v qh1 = *(const short8v*)(qpH + 32);
  short8v qlo0 = *(const short8v*)(qpL);
  short8v qlo1 = *(const short8v*)(qpL + 32);

  const unsigned short* kpH = Kh + hoff;
  const unsigned short* kpL = Kl + hoff;
  const unsigned short* vpH = Vh + hoff;
  const unsigned short* vpL = Vl + hoff;

  float mrow[4], lsum[4];
  f32x4 O[4];
#pragma unroll
  for (int i = 0; i < 4; i++) { mrow[i] = -1e30f; lsum[i] = 0.f; }
#pragma unroll
  for (int df = 0; df < 4; df++) O[df] = {0.f, 0.f, 0.f, 0.f};

  unsigned short* PH = &Pb[w][0][0];
  unsigned short* PL = &Pb[w][1][0];

  for (int kt = 0; kt < SEQ / 64; kt++) {
    int key0 = kt * 64;
    // stage K row-major (coalesced global, conflict-free LDS via 72-pad)
#pragma unroll
    for (int it = 0; it < 2; it++) {
      int idx = t + it * 256;
      int kk = idx >> 3, ch = idx & 7;
      short8v a = *(const short8v*)(kpH + (size_t)(key0 + kk) * DIMD + ch * 8);
      short8v bb = *(const short8v*)(kpL + (size_t)(key0 + kk) * DIMD + ch * 8);
      *(short8v*)&KsH[kk * 72 + ch * 8] = a;
      *(short8v*)&KsL[kk * 72 + ch * 8] = bb;
    }
    // stage V transposed: Vt[dh][key] (contiguous u16 row writes, conflict-free)
#pragma unroll
    for (int it = 0; it < 2; it++) {
      int ch = (t >> 6) + it * 4;
      int kk = t & 63;
      short8v a = *(const short8v*)(vpH + (size_t)(key0 + kk) * DIMD + ch * 8);
      short8v bb = *(const short8v*)(vpL + (size_t)(key0 + kk) * DIMD + ch * 8);
#pragma unroll
      for (int j = 0; j < 8; j++) {
        VtH[(ch * 8 + j) * 72 + kk] = (unsigned short)a[j];
        VtL[(ch * 8 + j) * 72 + kk] = (unsigned short)bb[j];
      }
    }
    __syncthreads();

    // QK^T: s[kf] covers 16 queries x 16 keys, 6 MFMA each (3 split terms x 2 k-halves)
    f32x4 s[4];
#pragma unroll
    for (int kf = 0; kf < 4; kf++) {
      int base = (kf * 16 + lr) * 72 + lg * 8;
      short8v kh0 = *(const short8v*)&KsH[base];
      short8v kh1 = *(const short8v*)&KsH[base + 32];
      short8v kl0 = *(const short8v*)&KsL[base];
      short8v kl1 = *(const short8v*)&KsL[base + 32];
      f32x4 acc = {0.f, 0.f, 0.f, 0.f};
      acc = __builtin_amdgcn_mfma_f32_16x16x32_bf16(qh0, kh0, acc, 0, 0, 0);
      acc = __builtin_amdgcn_mfma_f32_16x16x32_bf16(qh1, kh1, acc, 0, 0, 0);
      acc = __builtin_amdgcn_mfma_f32_16x16x32_bf16(qh0, kl0, acc, 0, 0, 0);
      acc = __builtin_amdgcn_mfma_f32_16x16x32_bf16(qh1, kl1, acc, 0, 0, 0);
      acc = __builtin_amdgcn_mfma_f32_16x16x32_bf16(qlo0, kh0, acc, 0, 0, 0);
      acc = __builtin_amdgcn_mfma_f32_16x16x32_bf16(qlo1, kh1, acc, 0, 0, 0);
      s[kf] = acc;
    }
    // tile softmax: row stats via 16-lane group reduce (rows = lg*4+i)
    float alpha[4];
#pragma unroll
    for (int i = 0; i < 4; i++) {
      float mx = fmaxf(fmaxf(s[0][i], s[1][i]), fmaxf(s[2][i], s[3][i]));
      mx = fmaxf(mx, __shfl_xor(mx, 1));
      mx = fmaxf(mx, __shfl_xor(mx, 2));
      mx = fmaxf(mx, __shfl_xor(mx, 4));
      mx = fmaxf(mx, __shfl_xor(mx, 8));
      float mnew = fmaxf(mrow[i], mx);
      alpha[i] = __expf(mrow[i] - mnew);
      mrow[i] = mnew;
    }
    float rs[4] = {0.f, 0.f, 0.f, 0.f};
#pragma unroll
    for (int kf = 0; kf < 4; kf++) {
#pragma unroll
      for (int i = 0; i < 4; i++) {
        float p = __expf(s[kf][i] - mrow[i]);
        rs[i] += p;
        unsigned short hu, lu; splitf(p, hu, lu);
        int q = lg * 4 + i;
        PH[q * 72 + kf * 16 + lr] = hu;
        PL[q * 72 + kf * 16 + lr] = lu;
      }
    }
#pragma unroll
    for (int i = 0; i < 4; i++) {
      rs[i] += __shfl_xor(rs[i], 1);
      rs[i] += __shfl_xor(rs[i], 2);
      rs[i] += __shfl_xor(rs[i], 4);
      rs[i] += __shfl_xor(rs[i], 8);
      lsum[i] = lsum[i] * alpha[i] + rs[i];
    }
    // O rescale then PV (P roundtrip through per-wave LDS converts C->A layout)
#pragma unroll
    for (int df = 0; df < 4; df++)
#pragma unroll
      for (int i = 0; i < 4; i++) O[df][i] *= alpha[i];

    int pbase = lr * 72 + lg * 8;
    short8v ph0 = *(const short8v*)&PH[pbase];
    short8v ph1 = *(const short8v*)&PH[pbase + 32];
    short8v pl0 = *(const short8v*)&PL[pbase];
    short8v pl1 = *(const short8v*)&PL[pbase + 32];
#pragma unroll
    for (int df = 0; df < 4; df++) {
      int vb = (df * 16 + lr) * 72 + lg * 8;
      short8v vh0 = *(const short8v*)&VtH[vb];
      short8v vh1 = *(const short8v*)&VtH[vb + 32];
      short8v vl0 = *(const short8v*)&VtL[vb];
      short8v vl1 = *(const short8v*)&VtL[vb + 32];
      f32x4 acc = O[df];
      acc = __builtin_amdgcn_mfma_f32_16x16x32_bf16(ph0, vh0, acc, 0, 0, 0);
      acc = __builtin_amdgcn_mfma_f32_16x16x32_bf16(ph1, vh1, acc, 0, 0, 0);
      acc = __builtin_amdgcn_mfma_f32_16x16x32_bf16(ph0, vl0, acc, 0, 0, 0);
      acc = __builtin_amdgcn_mfma_f32_16x16x32_bf16(ph1, vl1, acc, 0, 0, 0);
      acc = __builtin_amdgcn_mfma_f32_16x16x32_bf16(pl0, vh0, acc, 0, 0, 0);
      acc = __builtin_amdgcn_mfma_f32_16x16x32_bf16(pl1, vh1, acc, 0, 0, 0);
      O[df] = acc;
    }
    __syncthreads();
  }
  // epilogue: O/l -> bf16 hi/lo planes
#pragma unroll
  for (int i = 0; i < 4; i++) {
    float inv = 1.0f / lsum[i];
    int row = q0 + lg * 4 + i;
#pragma unroll
    for (int df = 0; df < 4; df++) {
      float v = O[df][i] * inv;
      unsigned short hu, lu; splitf(v, hu, lu);
      size_t off = hoff + (size_t)row * DIMD + df * 16 + lr;
      ATTh[off] = hu;
      ATTl[off] = lu;
    }
  }
}

// ---------------- FFN1: H[enc] = relu(OUT1[token]@W1c + b1) -> bf16 hi/lo ----------------
__global__ __launch_bounds__(256, 2) void ffn1_mfma(
    const unsigned short* __restrict__ Ah, const unsigned short* __restrict__ Al,
    const unsigned short* __restrict__ Bh, const unsigned short* __restrict__ Bl,
    const float* __restrict__ b1c,
    unsigned short* __restrict__ Hh, unsigned short* __restrict__ Hl,
    const int* __restrict__ lists, const int* __restrict__ counts) {
  int e = blockIdx.z;
  int cnt = counts[e];
  int m0 = blockIdx.x * 128;
  if (m0 >= cnt) return;
  __shared__ unsigned short lds[12288];
  __shared__ int rowenc[128];
  int t = threadIdx.x;
  if (t < 128) {
    int r = m0 + t;
    rowenc[t] = (r < cnt) ? lists[e * TTOK + r] : -1;
  }
  __syncthreads();
  int w = t >> 6, l = t & 63;
  int wr = w >> 1, wc = w & 1;
  int n0 = blockIdx.y * 64;
  f32x4 acc[4][2];
#pragma unroll
  for (int mf = 0; mf < 4; mf++)
#pragma unroll
    for (int nf = 0; nf < 2; nf++) acc[mf][nf] = {0.f, 0.f, 0.f, 0.f};
  int kb = (l >> 4) << 3;
  int enc0 = rowenc[(w * 2 + 0) * 16 + (l & 15)];
  int enc1 = rowenc[(w * 2 + 1) * 16 + (l & 15)];
  size_t rowoff0 = (size_t)(enc0 >= 0 ? (enc0 >> 1) : 0) * 512 + kb;
  size_t rowoff1 = (size_t)(enc1 >= 0 ? (enc1 >> 1) : 0) * 512 + kb;
  size_t bbase = (size_t)e * 262144 + (size_t)(((n0 >> 4) + w) * 64 + l) * 8;
  mfma_loop(Ah, Al, rowoff0, rowoff1, Bh, Bl, bbase, lds, w, l, wr, wc, acc);
#pragma unroll
  for (int nf = 0; nf < 2; nf++) {
    int col = n0 + (wc * 2 + nf) * 16 + (l & 15);
    float bv = b1c[e * NFF + col];
#pragma unroll
    for (int mf = 0; mf < 4; mf++) {
      int lrow = (wr * 4 + mf) * 16 + ((l >> 4) << 2);
#pragma unroll
      for (int i = 0; i < 4; i++) {
        int enc = rowenc[lrow + i];
        if (enc >= 0) {
          float v = fmaxf(acc[mf][nf][i] + bv, 0.f);
          unsigned short hu, lu; splitf(v, hu, lu);
          Hh[(size_t)enc * 512 + col] = hu;
          Hl[(size_t)enc * 512 + col] = lu;
        }
      }
    }
  }
}

// ---------------- FFN2: Oslot[enc] (c==0? =bias+ : +=) H[enc] @ W2c ----------------
__global__ __launch_bounds__(256, 2) void ffn2_mfma(
    const unsigned short* __restrict__ Ah, const unsigned short* __restrict__ Al,
    const unsigned short* __restrict__ Bh, const unsigned short* __restrict__ Bl,
    const float* __restrict__ b2i,
    float* __restrict__ OS0, float* __restrict__ OS1,
    const int* __restrict__ lists, const int* __restrict__ counts, int c) {
  int e = blockIdx.z;
  int cnt = counts[e];
  int m0 = blockIdx.x * 128;
  if (m0 >= cnt) return;
  __shared__ unsigned short lds[12288];
  __shared__ int rowenc[128];
  int t = threadIdx.x;
  if (t < 128) {
    int r = m0 + t;
    rowenc[t] = (r < cnt) ? lists[e * TTOK + r] : -1;
  }
  __syncthreads();
  int w = t >> 6, l = t & 63;
  int wr = w >> 1, wc = w & 1;
  int n0 = blockIdx.y * 64;
  f32x4 acc[4][2];
#pragma unroll
  for (int mf = 0; mf < 4; mf++)
#pragma unroll
    for (int nf = 0; nf < 2; nf++) acc[mf][nf] = {0.f, 0.f, 0.f, 0.f};
  int kb = (l >> 4) << 3;
  int enc0 = rowenc[(w * 2 + 0) * 16 + (l & 15)];
  int enc1 = rowenc[(w * 2 + 1) * 16 + (l & 15)];
  size_t rowoff0 = (size_t)(enc0 >= 0 ? enc0 : 0) * 512 + kb;
  size_t rowoff1 = (size_t)(enc1 >= 0 ? enc1 : 0) * 512 + kb;
  size_t bbase = (size_t)e * 262144 + (size_t)(((n0 >> 4) + w) * 64 + l) * 8;
  mfma_loop(Ah, Al, rowoff0, rowoff1, Bh, Bl, bbase, lds, w, l, wr, wc, acc);
#pragma unroll
  for (int nf = 0; nf < 2; nf++) {
    int col = n0 + (wc * 2 + nf) * 16 + (l & 15);
    float bv = b2i[e * DIMD + col];
#pragma unroll
    for (int mf = 0; mf < 4; mf++) {
      int lrow = (wr * 4 + mf) * 16 + ((l >> 4) << 2);
#pragma unroll
      for (int i = 0; i < 4; i++) {
        int enc = rowenc[lrow + i];
        if (enc >= 0) {
          float* dst = (enc < 8192 ? OS0 + (size_t)enc * 512
                                   : OS1 + (size_t)(enc - 8192) * 512) + col;
          float v = acc[mf][nf][i];
          if (c == 0) v += bv; else v += *dst;
          *dst = v;
        }
      }
    }
  }
}

// ---------------- LayerNorm((Xh+Xl) + p) * g + be -> bf16 hi/lo ----------------
__global__ __launch_bounds__(256) void ln_add_kernel(
    const unsigned short* __restrict__ Xh, const unsigned short* __restrict__ Xl,
    const float* __restrict__ p,
    const float* __restrict__ g, const float* __restrict__ be,
    unsigned short* __restrict__ outH, unsigned short* __restrict__ outL) {
  int wave = threadIdx.x >> 6;
  int lane = threadIdx.x & 63;
  int token = blockIdx.x * 4 + wave;
  short8v h8 = *(const short8v*)(Xh + (size_t)token * 512 + lane * 8);
  short8v l8 = *(const short8v*)(Xl + (size_t)token * 512 + lane * 8);
  const float* pr = p + (size_t)token * 512 + lane * 8;
  float pv[8];
  *(float4*)(&pv[0]) = *(const float4*)(pr);
  *(float4*)(&pv[4]) = *(const float4*)(pr + 4);
  float vals[8];
  float sum = 0.0f;
#pragma unroll
  for (int j = 0; j < 8; j++) {
    float v = bf2f((unsigned short)h8[j]) + bf2f((unsigned short)l8[j]) + pv[j];
    vals[j] = v; sum += v;
  }
#pragma unroll
  for (int off = 32; off; off >>= 1) sum += __shfl_xor(sum, off);
  float mu = sum * (1.0f / 512.0f);
  float sq = 0.0f;
#pragma unroll
  for (int j = 0; j < 8; j++) { vals[j] -= mu; sq += vals[j] * vals[j]; }
#pragma unroll
  for (int off = 32; off; off >>= 1) sq += __shfl_xor(sq, off);
  float rs = rsqrtf(sq * (1.0f / 512.0f) + 1e-6f);
  short8v oh, ol;
#pragma unroll
  for (int j = 0; j < 8; j++) {
    int d = lane * 8 + j;
    float y = vals[j] * rs * g[d] + be[d];
    unsigned short hu, lu; splitf(y, hu, lu);
    oh[j] = (short)hu; ol[j] = (short)lu;
  }
  *(short8v*)(outH + (size_t)token * 512 + lane * 8) = oh;
  *(short8v*)(outL + (size_t)token * 512 + lane * 8) = ol;
}

// ---------------- LayerNorm(OUT1 + g0*o0 + g1*o1) -> fp32 (last) or bf16 hi/lo ----------
__global__ __launch_bounds__(256) void ln_moe_kernel(
    const unsigned short* __restrict__ O1h, const unsigned short* __restrict__ O1l,
    const float* __restrict__ OS0, const float* __restrict__ OS1,
    const float* __restrict__ gates, const float* __restrict__ g,
    const float* __restrict__ be, float* __restrict__ outF,
    unsigned short* __restrict__ outH, unsigned short* __restrict__ outL) {
  int wave = threadIdx.x >> 6;
  int lane = threadIdx.x & 63;
  int token = blockIdx.x * 4 + wave;
  short8v h8 = *(const short8v*)(O1h + (size_t)token * 512 + lane * 8);
  short8v l8 = *(const short8v*)(O1l + (size_t)token * 512 + lane * 8);
  const float* ob = (token < 4096) ? (OS0 + (size_t)token * 1024)
                                   : (OS1 + ((size_t)token - 4096) * 1024);
  const float* o0 = ob + lane * 8;
  const float* o1 = ob + 512 + lane * 8;
  float gate0 = gates[token * 2], gate1 = gates[token * 2 + 1];
  float a0[8], a1[8];
  *(float4*)(&a0[0]) = *(const float4*)(o0);
  *(float4*)(&a0[4]) = *(const float4*)(o0 + 4);
  *(float4*)(&a1[0]) = *(const float4*)(o1);
  *(float4*)(&a1[4]) = *(const float4*)(o1 + 4);
  float vals[8];
  float sum = 0.0f;
#pragma unroll
  for (int j = 0; j < 8; j++) {
    float v = bf2f((unsigned short)h8[j]) + bf2f((unsigned short)l8[j]) +
              gate0 * a0[j] + gate1 * a1[j];
    vals[j] = v; sum += v;
  }
#pragma unroll
  for (int off = 32; off; off >>= 1) sum += __shfl_xor(sum, off);
  float mu = sum * (1.0f / 512.0f);
  float sq = 0.0f;
#pragma unroll
  for (int j = 0; j < 8; j++) { vals[j] -= mu; sq += vals[j] * vals[j]; }
#pragma unroll
  for (int off = 32; off; off >>= 1) sq += __shfl_xor(sq, off);
  float rs = rsqrtf(sq * (1.0f / 512.0f) + 1e-6f);
  if (outF) {
#pragma unroll
    for (int j = 0; j < 8; j++) {
      int d = lane * 8 + j;
      outF[(size_t)token * 512 + d] = vals[j] * rs * g[d] + be[d];
    }
  } else {
    short8v oh, ol;
#pragma unroll
    for (int j = 0; j < 8; j++) {
      int d = lane * 8 + j;
      float y = vals[j] * rs * g[d] + be[d];
      unsigned short hu, lu; splitf(y, hu, lu);
      oh[j] = (short)hu; ol[j] = (short)lu;
    }
    *(short8v*)(outH + (size_t)token * 512 + lane * 8) = oh;
    *(short8v*)(outL + (size_t)token * 512 + lane * 8) = ol;
  }
}

// ---------------- MoE routing: softmax top-2 + bucket by expert ----------------
__global__ __launch_bounds__(256) void route_kernel(
    const unsigned short* __restrict__ Xh, const unsigned short* __restrict__ Xl,
    const float* __restrict__ Wg, const float* __restrict__ bg,
    float* __restrict__ gates, int* __restrict__ lists, int* __restrict__ counts) {
  int wave = threadIdx.x >> 6;
  int lane = threadIdx.x & 63;
  int token = blockIdx.x * 4 + wave;
  float acc[8];
#pragma unroll
  for (int e = 0; e < 8; e++) acc[e] = 0.0f;
  for (int it = 0; it < 8; it++) {
    int d = it * 64 + lane;
    float xv = bf2f(Xh[(size_t)token * 512 + d]) + bf2f(Xl[(size_t)token * 512 + d]);
    float4 w0 = *(const float4*)(Wg + d * 8);
    float4 w1 = *(const float4*)(Wg + d * 8 + 4);
    acc[0] += xv * w0.x; acc[1] += xv * w0.y;
    acc[2] += xv * w0.z; acc[3] += xv * w0.w;
    acc[4] += xv * w1.x; acc[5] += xv * w1.y;
    acc[6] += xv * w1.z; acc[7] += xv * w1.w;
  }
#pragma unroll
  for (int e = 0; e < 8; e++)
#pragma unroll
    for (int off = 32; off; off >>= 1) acc[e] += __shfl_xor(acc[e], off);
  if (lane == 0) {
    float lg[8];
    float mx = -1e30f;
#pragma unroll
    for (int e = 0; e < 8; e++) { lg[e] = acc[e] + bg[e]; mx = fmaxf(mx, lg[e]); }
#pragma unroll
    for (int e = 0; e < 8; e++) lg[e] = __expf(lg[e] - mx);
    int i0 = 0; float v0 = lg[0];
#pragma unroll
    for (int e = 1; e < 8; e++) if (lg[e] > v0) { v0 = lg[e]; i0 = e; }
    int i1 = -1; float v1 = -1.0f;
#pragma unroll
    for (int e = 0; e < 8; e++)
      if (e != i0 && lg[e] > v1) { v1 = lg[e]; i1 = e; }
    float inv = 1.0f / (v0 + v1);
    gates[token * 2] = v0 * inv;
    gates[token * 2 + 1] = v1 * inv;
    int p0 = atomicAdd(&counts[i0], 1);
    lists[i0 * TTOK + p0] = token * 2;
    int p1 = atomicAdd(&counts[i1], 1);
    lists[i1 * TTOK + p1] = token * 2 + 1;
  }
}

__global__ void zero_counts_kernel(int* counts) {
  if (threadIdx.x < NEXP) counts[threadIdx.x] = 0;
}

// ---------------- host orchestration ----------------
// Workspace (aliased by phase; ~100.4 MB):
//  [0..16M)    Xh(8M)+Xl(8M)              | Hl (MoE)
//  [16..32M)   Qh(8M)+Ql(8M)              | W1c/W2c images (4 x 4M)
//  [32..48M)   Kh(8M)+Kl(8M)              | PROJ fp32 | OS0
//  [48..64M)   Vh(8M)+Vl(8M)              | OUT1h+OUT1l
//  [64..80M)   ATTh(8M)+ATTl(8M)          | Hh (MoE)
//  [80..84M)   Wq/Wk/Wv/Wo images
//  [84..100M)  OS1
//  [100M..)    GATES LISTS COUNTS
extern "C" void kernel_launch(void* const* d_in, const int* in_sizes, int n_in,
                              void* d_out, int out_size, void* d_ws, size_t ws_size,
                              hipStream_t stream) {
  (void)in_sizes; (void)n_in; (void)out_size; (void)ws_size;
  const int*   tokens = (const int*)d_in[0];
  const float* emb = (const float*)d_in[1];
  const float* Wq = (const float*)d_in[2];
  const float* bq = (const float*)d_in[3];
  const float* Wk = (const float*)d_in[4];
  const float* bk = (const float*)d_in[5];
  const float* Wv = (const float*)d_in[6];
  const float* bv = (const float*)d_in[7];
  const float* Wo = (const float*)d_in[8];
  const float* bo = (const float*)d_in[9];
  const float* Wg = (const float*)d_in[10];
  const float* bg = (const float*)d_in[11];
  const float* W1 = (const float*)d_in[12];
  const float* b1 = (const float*)d_in[13];
  const float* W2 = (const float*)d_in[14];
  const float* b2 = (const float*)d_in[15];
  const float* g1 = (const float*)d_in[16];
  const float* be1 = (const float*)d_in[17];
  const float* g2 = (const float*)d_in[18];
  const float* be2 = (const float*)d_in[19];

  char* base = (char*)d_ws;
  const size_t MB = 1024u * 1024u;
  unsigned short* Xh   = (unsigned short*)(base + 0 * MB);
  unsigned short* Xl   = (unsigned short*)(base + 8 * MB);
  unsigned short* Hl   = (unsigned short*)(base + 0 * MB);
  unsigned short* Qh   = (unsigned short*)(base + 16 * MB);
  unsigned short* Ql   = (unsigned short*)(base + 24 * MB);
  unsigned short* W1h  = (unsigned short*)(base + 16 * MB);
  unsigned short* W1l  = (unsigned short*)(base + 20 * MB);
  unsigned short* W2h  = (unsigned short*)(base + 24 * MB);
  unsigned short* W2l  = (unsigned short*)(base + 28 * MB);
  unsigned short* Kh   = (unsigned short*)(base + 32 * MB);
  unsigned short* Kl   = (unsigned short*)(base + 40 * MB);
  float*          PROJ = (float*)(base + 32 * MB);
  float*          OS0  = (float*)(base + 32 * MB);
  unsigned short* Vh   = (unsigned short*)(base + 48 * MB);
  unsigned short* Vl   = (unsigned short*)(base + 56 * MB);
  unsigned short* O1h  = (unsigned short*)(base + 48 * MB);
  unsigned short* O1l  = (unsigned short*)(base + 56 * MB);
  unsigned short* ATTh = (unsigned short*)(base + 64 * MB);
  unsigned short* ATTl = (unsigned short*)(base + 72 * MB);
  unsigned short* Hh   = (unsigned short*)(base + 64 * MB);
  unsigned short* Wimg = (unsigned short*)(base + 80 * MB);
  float*          OS1  = (float*)(base + 84 * MB);
  float*          GATES = (float*)(base + 100 * MB);
  int*            LISTS = (int*)(base + 100 * MB + 65536);
  int*            COUNTS = (int*)(base + 100 * MB + 65536 + 262144);

  const size_t WPL = 262144;  // ushorts per 512x512 weight plane

  dim3 blk(256);
  embed_kernel<<<(TTOK * DIMD) / 256, blk, 0, stream>>>(tokens, emb, Xh, Xl);

  for (int i = 0; i < NLAYER; i++) {
    const float* wq = Wq + (size_t)i * DIMD * DIMD;
    const float* wk = Wk + (size_t)i * DIMD * DIMD;
    const float* wv = Wv + (size_t)i * DIMD * DIMD;
    const float* wo = Wo + (size_t)i * DIMD * DIMD;
    const float* bqi = bq + (size_t)i * DIMD;
    const float* bki = bk + (size_t)i * DIMD;
    const float* bvi = bv + (size_t)i * DIMD;
    const float* boi = bo + (size_t)i * DIMD;
    const float* wgi = Wg + (size_t)i * DIMD * NEXP;
    const float* bgi = bg + (size_t)i * NEXP;
    const float* w1i = W1 + (size_t)i * NEXP * DIMD * NFF;
    const float* b1i = b1 + (size_t)i * NEXP * NFF;
    const float* w2i = W2 + (size_t)i * NEXP * NFF * DIMD;
    const float* b2i = b2 + (size_t)i * NEXP * DIMD;
    const float* g1i = g1 + (size_t)i * DIMD;
    const float* be1i = be1 + (size_t)i * DIMD;
    const float* g2i = g2 + (size_t)i * DIMD;
    const float* be2i = be2 + (size_t)i * DIMD;

    conv_w_kernel<<<dim3(128, 1, 1), blk, 0, stream>>>(wq, 512, 0, Wimg + 0 * WPL, Wimg + 1 * WPL);
    conv_w_kernel<<<dim3(128, 1, 1), blk, 0, stream>>>(wk, 512, 0, Wimg + 2 * WPL, Wimg + 3 * WPL);
    conv_w_kernel<<<dim3(128, 1, 1), blk, 0, stream>>>(wv, 512, 0, Wimg + 4 * WPL, Wimg + 5 * WPL);
    conv_w_kernel<<<dim3(128, 1, 1), blk, 0, stream>>>(wo, 512, 0, Wimg + 6 * WPL, Wimg + 7 * WPL);

    dim3 gg(64, 8);
    gemm_dense_bf<<<gg, blk, 0, stream>>>(Xh, Xl, Wimg + 0 * WPL, Wimg + 1 * WPL, bqi, Qh, Ql, 0.125f);
    gemm_dense_bf<<<gg, blk, 0, stream>>>(Xh, Xl, Wimg + 2 * WPL, Wimg + 3 * WPL, bki, Kh, Kl, 1.0f);
    gemm_dense_bf<<<gg, blk, 0, stream>>>(Xh, Xl, Wimg + 4 * WPL, Wimg + 5 * WPL, bvi, Vh, Vl, 1.0f);
    attn_mfma<<<dim3(SEQ / 64, 32), blk, 0, stream>>>(Qh, Ql, Kh, Kl, Vh, Vl, ATTh, ATTl);
    gemm_dense<<<gg, blk, 0, stream>>>(ATTh, ATTl, Wimg + 6 * WPL, Wimg + 7 * WPL, boi, PROJ);

    ln_add_kernel<<<TTOK / 4, blk, 0, stream>>>(Xh, Xl, PROJ, g1i, be1i, O1h, O1l);
    zero_counts_kernel<<<1, 64, 0, stream>>>(COUNTS);
    route_kernel<<<TTOK / 4, blk, 0, stream>>>(O1h, O1l, wgi, bgi, GATES, LISTS, COUNTS);

    for (int c = 0; c < 4; c++) {
      conv_w_kernel<<<dim3(128, 1, 8), blk, 0, stream>>>(
          w1i + c * 512, NFF, (size_t)DIMD * NFF, W1h, W1l);
      conv_w_kernel<<<dim3(128, 1, 8), blk, 0, stream>>>(
          w2i + (size_t)c * 512 * DIMD, DIMD, (size_t)NFF * DIMD, W2h, W2l);
      ffn1_mfma<<<dim3(64, 8, 8), blk, 0, stream>>>(
          O1h, O1l, W1h, W1l, b1i + c * 512, Hh, Hl, LISTS, COUNTS);
      ffn2_mfma<<<dim3(64, 8, 8), blk, 0, stream>>>(
          Hh, Hl, W2h, W2l, b2i, OS0, OS1, LISTS, COUNTS, c);
    }
    float* xout = (i == NLAYER - 1) ? (float*)d_out : nullptr;
    ln_moe_kernel<<<TTOK / 4, blk, 0, stream>>>(
        O1h, O1l, OS0, OS1, GATES, g2i, be2i, xout, Xh, Xl);
  }
}

// Round 5
// 5644.208 us; speedup vs baseline: 1.5365x; 1.0157x over previous
//
#include <hip/hip_runtime.h>
#include <math.h>

#define TTOK 8192   // B*S
#define DIMD 512
#define NHEAD 8
#define DHEAD 64
#define SEQ 2048
#define NEXP 8
#define NFF 2048
#define NLAYER 4
#define WPL 262144  // ushorts per 512x512 weight plane

typedef __attribute__((ext_vector_type(8))) short short8v;   // 8 bf16 (4 VGPRs)
typedef __attribute__((ext_vector_type(4))) float f32x4;     // MFMA 16x16 accum

__device__ __forceinline__ float bf2f(unsigned short h) {
  union { unsigned u; float f; } c; c.u = ((unsigned)h) << 16; return c.f;
}
// split fp32 into truncated-bf16 hi + bf16(lo) ; a ~= hi + lo with ~2^-17 rel err
__device__ __forceinline__ void splitf(float v, unsigned short& hi, unsigned short& lo) {
  union { float f; unsigned u; } a; a.f = v;
  hi = (unsigned short)(a.u >> 16);
  union { unsigned u; float f; } b; b.u = a.u & 0xFFFF0000u;
  union { float f; unsigned u; } c; c.f = v - b.f;   // exact
  lo = (unsigned short)(c.u >> 16);
}

// ---------------- embedding + positional encoding -> bf16 hi/lo planes ----------------
__global__ __launch_bounds__(256) void embed_kernel(
    const int* __restrict__ tokens, const float* __restrict__ emb,
    unsigned short* __restrict__ Xh, unsigned short* __restrict__ Xl) {
  int idx = blockIdx.x * 256 + threadIdx.x;       // over TTOK*DIMD
  int t = idx >> 9;
  int d = idx & 511;
  int s = t & (SEQ - 1);
  int tok = tokens[t];
  float j2 = (float)((d >> 1) << 1);
  float freq = expf(-j2 * (9.210340371976184f / 512.0f));
  float angle = (float)s * freq;
  float pe = (d & 1) ? cosf(angle) : sinf(angle);
  float v = emb[tok * DIMD + d] * 22.627416997969522f + pe;
  unsigned short hu, lu; splitf(v, hu, lu);
  Xh[idx] = hu; Xl[idx] = lu;
}

// ---------------- weight converter core: fp32 [K=512][N=512 of ld] -> fragment image --
// img layout: [kt 0..15][nf 0..31][lane 0..63][8 bf16]
// slot (kt,nf,lane): element j = W[kt*32 + (lane>>4)*8 + j][nf*16 + (lane&15)]
__device__ __forceinline__ void conv_body(
    const float* __restrict__ src, int ld, int s,
    unsigned short* __restrict__ hi, unsigned short* __restrict__ lo) {
  int kt = s >> 11;
  int rem = s & 2047;
  int nf = rem >> 6;
  int l = rem & 63;
  int k = kt * 32 + ((l >> 4) << 3);
  int n = (nf << 4) + (l & 15);
  const float* p = src + (size_t)k * ld + n;
  short8v h8, l8;
#pragma unroll
  for (int j = 0; j < 8; j++) {
    float v = p[(size_t)j * ld];
    unsigned short hu, lu; splitf(v, hu, lu);
    h8[j] = (short)hu; l8[j] = (short)lu;
  }
  *(short8v*)(hi + (size_t)s * 8) = h8;
  *(short8v*)(lo + (size_t)s * 8) = l8;
}

// fused q/k/v/o converter: grid (128, 4)
__global__ __launch_bounds__(256) void conv_qkvo_kernel(
    const float* __restrict__ Wq, const float* __restrict__ Wk,
    const float* __restrict__ Wv, const float* __restrict__ Wo,
    unsigned short* __restrict__ Wimg) {
  int y = blockIdx.y;
  const float* src = (y == 0) ? Wq : (y == 1) ? Wk : (y == 2) ? Wv : Wo;
  unsigned short* hi = Wimg + (size_t)y * 2 * WPL;
  unsigned short* lo = hi + WPL;
  int s = blockIdx.x * 256 + threadIdx.x;
  conv_body(src, 512, s, hi, lo);
}

// fused per-chunk W1/W2 converter over 8 experts: grid (128, 2, 8)
__global__ __launch_bounds__(256) void conv_w12_kernel(
    const float* __restrict__ w1c, const float* __restrict__ w2c,
    unsigned short* __restrict__ W1h, unsigned short* __restrict__ W1l,
    unsigned short* __restrict__ W2h, unsigned short* __restrict__ W2l) {
  int y = blockIdx.y;
  int e = blockIdx.z;
  int s = blockIdx.x * 256 + threadIdx.x;
  if (y == 0) {
    conv_body(w1c + (size_t)e * DIMD * NFF, NFF, s,
              W1h + (size_t)e * WPL, W1l + (size_t)e * WPL);
  } else {
    conv_body(w2c + (size_t)e * NFF * DIMD, DIMD, s,
              W2h + (size_t)e * WPL, W2l + (size_t)e * WPL);
  }
}

// ---------------- shared bf16x3 MFMA K-loop (K=512, BM=128, BN=64, BK=32) ------------
__device__ __forceinline__ void mfma_loop(
    const unsigned short* __restrict__ Ah, const unsigned short* __restrict__ Al,
    size_t rowoff0, size_t rowoff1,
    const unsigned short* __restrict__ Bh, const unsigned short* __restrict__ Bl,
    size_t bbase, unsigned short* lds, int w, int l, int wr, int wc,
    f32x4 acc[4][2]) {
  const unsigned short* pBh = Bh + bbase;
  const unsigned short* pBl = Bl + bbase;
  short8v r0h, r1h, r0l, r1l, rbh, rbl;

#define LOADK(kt)                                               \
  r0h = *(const short8v*)(Ah + rowoff0 + (kt) * 32);            \
  r1h = *(const short8v*)(Ah + rowoff1 + (kt) * 32);            \
  r0l = *(const short8v*)(Al + rowoff0 + (kt) * 32);            \
  r1l = *(const short8v*)(Al + rowoff1 + (kt) * 32);            \
  rbh = *(const short8v*)(pBh + (size_t)(kt) * 16384);          \
  rbl = *(const short8v*)(pBl + (size_t)(kt) * 16384);

#define STOREK()                                                \
  *(short8v*)&lds[(w * 128 + l) * 8] = r0h;                     \
  *(short8v*)&lds[(w * 128 + 64 + l) * 8] = r1h;                \
  *(short8v*)&lds[(512 + w * 128 + l) * 8] = r0l;               \
  *(short8v*)&lds[(512 + w * 128 + 64 + l) * 8] = r1l;          \
  *(short8v*)&lds[(1024 + w * 64 + l) * 8] = rbh;               \
  *(short8v*)&lds[(1280 + w * 64 + l) * 8] = rbl;

#define COMPK()                                                                              \
  {                                                                                          \
    short8v BH0 = *(const short8v*)&lds[(1024 + (wc * 2 + 0) * 64 + l) * 8];                 \
    short8v BL0 = *(const short8v*)&lds[(1280 + (wc * 2 + 0) * 64 + l) * 8];                 \
    short8v BH1 = *(const short8v*)&lds[(1024 + (wc * 2 + 1) * 64 + l) * 8];                 \
    short8v BL1 = *(const short8v*)&lds[(1280 + (wc * 2 + 1) * 64 + l) * 8];                 \
    _Pragma("unroll")                                                                        \
    for (int mf = 0; mf < 4; mf++) {                                                         \
      short8v AH = *(const short8v*)&lds[(((wr * 4 + mf) * 64) + l) * 8];                    \
      short8v AL2 = *(const short8v*)&lds[((512 + (wr * 4 + mf) * 64) + l) * 8];             \
      acc[mf][0] = __builtin_amdgcn_mfma_f32_16x16x32_bf16(AH, BH0, acc[mf][0], 0, 0, 0);    \
      acc[mf][0] = __builtin_amdgcn_mfma_f32_16x16x32_bf16(AH, BL0, acc[mf][0], 0, 0, 0);    \
      acc[mf][0] = __builtin_amdgcn_mfma_f32_16x16x32_bf16(AL2, BH0, acc[mf][0], 0, 0, 0);   \
      acc[mf][1] = __builtin_amdgcn_mfma_f32_16x16x32_bf16(AH, BH1, acc[mf][1], 0, 0, 0);    \
      acc[mf][1] = __builtin_amdgcn_mfma_f32_16x16x32_bf16(AH, BL1, acc[mf][1], 0, 0, 0);    \
      acc[mf][1] = __builtin_amdgcn_mfma_f32_16x16x32_bf16(AL2, BH1, acc[mf][1], 0, 0, 0);   \
    }                                                                                        \
  }

  LOADK(0);
  STOREK();
  __syncthreads();
  for (int kt = 0; kt < 15; kt++) {
    LOADK(kt + 1);
    COMPK();
    __syncthreads();
    STOREK();
    __syncthreads();
  }
  COMPK();
#undef LOADK
#undef STOREK
#undef COMPK
}

// ---------------- dense GEMM, fp32 out: C = A(hi/lo) @ Bimg + bias ----------------
__global__ __launch_bounds__(256, 2) void gemm_dense(
    const unsigned short* __restrict__ Ah, const unsigned short* __restrict__ Al,
    const unsigned short* __restrict__ Bh, const unsigned short* __restrict__ Bl,
    const float* __restrict__ bias, float* __restrict__ C) {
  __shared__ unsigned short lds[12288];
  int t = threadIdx.x;
  int w = t >> 6, l = t & 63;
  int wr = w >> 1, wc = w & 1;
  int m0 = blockIdx.x * 128;
  int n0 = blockIdx.y * 64;
  f32x4 acc[4][2];
#pragma unroll
  for (int mf = 0; mf < 4; mf++)
#pragma unroll
    for (int nf = 0; nf < 2; nf++) acc[mf][nf] = {0.f, 0.f, 0.f, 0.f};
  int kb = (l >> 4) << 3;
  size_t rowoff0 = (size_t)(m0 + (w * 2 + 0) * 16 + (l & 15)) * 512 + kb;
  size_t rowoff1 = (size_t)(m0 + (w * 2 + 1) * 16 + (l & 15)) * 512 + kb;
  size_t bbase = (size_t)(((n0 >> 4) + w) * 64 + l) * 8;
  mfma_loop(Ah, Al, rowoff0, rowoff1, Bh, Bl, bbase, lds, w, l, wr, wc, acc);
#pragma unroll
  for (int nf = 0; nf < 2; nf++) {
    int col = n0 + (wc * 2 + nf) * 16 + (l & 15);
    float bv = bias[col];
#pragma unroll
    for (int mf = 0; mf < 4; mf++) {
      int row = m0 + (wr * 4 + mf) * 16 + ((l >> 4) << 2);
#pragma unroll
      for (int i = 0; i < 4; i++)
        C[(size_t)(row + i) * 512 + col] = acc[mf][nf][i] + bv;
    }
  }
}

// ---------------- fused QKV GEMM, bf16 hi/lo out; z picks matrix ----------------
__global__ __launch_bounds__(256, 2) void gemm_qkv(
    const unsigned short* __restrict__ Ah, const unsigned short* __restrict__ Al,
    const unsigned short* __restrict__ Wimg,
    const float* __restrict__ bq, const float* __restrict__ bk,
    const float* __restrict__ bv,
    unsigned short* __restrict__ Qh, unsigned short* __restrict__ Ql,
    unsigned short* __restrict__ Kh, unsigned short* __restrict__ Kl,
    unsigned short* __restrict__ Vh, unsigned short* __restrict__ Vl) {
  __shared__ unsigned short lds[12288];
  int t = threadIdx.x;
  int w = t >> 6, l = t & 63;
  int wr = w >> 1, wc = w & 1;
  int m0 = blockIdx.x * 128;
  int n0 = blockIdx.y * 64;
  int z = blockIdx.z;
  const unsigned short* Bh = Wimg + (size_t)z * 2 * WPL;
  const unsigned short* Bl = Bh + WPL;
  const float* bias = (z == 0) ? bq : (z == 1) ? bk : bv;
  unsigned short* Ch = (z == 0) ? Qh : (z == 1) ? Kh : Vh;
  unsigned short* Cl = (z == 0) ? Ql : (z == 1) ? Kl : Vl;
  float scale = (z == 0) ? 0.125f : 1.0f;   // Q pre-scaled by 1/sqrt(64)
  f32x4 acc[4][2];
#pragma unroll
  for (int mf = 0; mf < 4; mf++)
#pragma unroll
    for (int nf = 0; nf < 2; nf++) acc[mf][nf] = {0.f, 0.f, 0.f, 0.f};
  int kb = (l >> 4) << 3;
  size_t rowoff0 = (size_t)(m0 + (w * 2 + 0) * 16 + (l & 15)) * 512 + kb;
  size_t rowoff1 = (size_t)(m0 + (w * 2 + 1) * 16 + (l & 15)) * 512 + kb;
  size_t bbase = (size_t)(((n0 >> 4) + w) * 64 + l) * 8;
  mfma_loop(Ah, Al, rowoff0, rowoff1, Bh, Bl, bbase, lds, w, l, wr, wc, acc);
#pragma unroll
  for (int nf = 0; nf < 2; nf++) {
    int col = n0 + (wc * 2 + nf) * 16 + (l & 15);
    float bv2 = bias[col];
#pragma unroll
    for (int mf = 0; mf < 4; mf++) {
      int row = m0 + (wr * 4 + mf) * 16 + ((l >> 4) << 2);
#pragma unroll
      for (int i = 0; i < 4; i++) {
        float v = (acc[mf][nf][i] + bv2) * scale;
        unsigned short hu, lu; splitf(v, hu, lu);
        Ch[(size_t)(row + i) * 512 + col] = hu;
        Cl[(size_t)(row + i) * 512 + col] = lu;
      }
    }
  }
}

// ---------------- MFMA flash attention (bf16x3 split, online softmax) ----------------
// 4 waves x 16 queries; 64-key tiles; K row-major LDS, V transposed LDS, both 72-pad.
__global__ __launch_bounds__(256, 2) void attn_mfma(
    const unsigned short* __restrict__ Qh, const unsigned short* __restrict__ Ql,
    const unsigned short* __restrict__ Kh, const unsigned short* __restrict__ Kl,
    const unsigned short* __restrict__ Vh, const unsigned short* __restrict__ Vl,
    unsigned short* __restrict__ ATTh, unsigned short* __restrict__ ATTl) {
  __shared__ __attribute__((aligned(16))) unsigned short KsH[64 * 72];
  __shared__ __attribute__((aligned(16))) unsigned short KsL[64 * 72];
  __shared__ __attribute__((aligned(16))) unsigned short VtH[64 * 72];
  __shared__ __attribute__((aligned(16))) unsigned short VtL[64 * 72];
  __shared__ __attribute__((aligned(16))) unsigned short Pb[4][2][16 * 72];
  int t = threadIdx.x;
  int w = t >> 6, l = t & 63;
  int lg = l >> 4, lr = l & 15;
  int qtile = blockIdx.x, bh = blockIdx.y;
  int b = bh >> 3, h = bh & 7;
  size_t hoff = (size_t)b * SEQ * DIMD + h * DHEAD;
  int q0 = qtile * 64 + w * 16;

  const unsigned short* qpH = Qh + hoff + (size_t)(q0 + lr) * DIMD + lg * 8;
  const unsigned short* qpL = Ql + hoff + (size_t)(q0 + lr) * DIMD + lg * 8;
  short8v qh0 = *(const short8v*)(qpH);
  short8v qh1 = *(const short8v*)(qpH + 32);
  short8v qlo0 = *(const short8v*)(qpL);
  short8v qlo1 = *(const short8v*)(qpL + 32);

  const unsigned short* kpH = Kh + hoff;
  const unsigned short* kpL = Kl + hoff;
  const unsigned short* vpH = Vh + hoff;
  const unsigned short* vpL = Vl + hoff;

  float mrow[4], lsum[4];
  f32x4 O[4];
#pragma unroll
  for (int i = 0; i < 4; i++) { mrow[i] = -1e30f; lsum[i] = 0.f; }
#pragma unroll
  for (int df = 0; df < 4; df++) O[df] = {0.f, 0.f, 0.f, 0.f};

  unsigned short* PH = &Pb[w][0][0];
  unsigned short* PL = &Pb[w][1][0];

  for (int kt = 0; kt < SEQ / 64; kt++) {
    int key0 = kt * 64;
#pragma unroll
    for (int it = 0; it < 2; it++) {
      int idx = t + it * 256;
      int kk = idx >> 3, ch = idx & 7;
      short8v a = *(const short8v*)(kpH + (size_t)(key0 + kk) * DIMD + ch * 8);
      short8v bb = *(const short8v*)(kpL + (size_t)(key0 + kk) * DIMD + ch * 8);
      *(short8v*)&KsH[kk * 72 + ch * 8] = a;
      *(short8v*)&KsL[kk * 72 + ch * 8] = bb;
    }
#pragma unroll
    for (int it = 0; it < 2; it++) {
      int ch = (t >> 6) + it * 4;
      int kk = t & 63;
      short8v a = *(const short8v*)(vpH + (size_t)(key0 + kk) * DIMD + ch * 8);
      short8v bb = *(const short8v*)(vpL + (size_t)(key0 + kk) * DIMD + ch * 8);
#pragma unroll
      for (int j = 0; j < 8; j++) {
        VtH[(ch * 8 + j) * 72 + kk] = (unsigned short)a[j];
        VtL[(ch * 8 + j) * 72 + kk] = (unsigned short)bb[j];
      }
    }
    __syncthreads();

    f32x4 s[4];
#pragma unroll
    for (int kf = 0; kf < 4; kf++) {
      int base = (kf * 16 + lr) * 72 + lg * 8;
      short8v kh0 = *(const short8v*)&KsH[base];
      short8v kh1 = *(const short8v*)&KsH[base + 32];
      short8v kl0 = *(const short8v*)&KsL[base];
      short8v kl1 = *(const short8v*)&KsL[base + 32];
      f32x4 acc = {0.f, 0.f, 0.f, 0.f};
      acc = __builtin_amdgcn_mfma_f32_16x16x32_bf16(qh0, kh0, acc, 0, 0, 0);
      acc = __builtin_amdgcn_mfma_f32_16x16x32_bf16(qh1, kh1, acc, 0, 0, 0);
      acc = __builtin_amdgcn_mfma_f32_16x16x32_bf16(qh0, kl0, acc, 0, 0, 0);
      acc = __builtin_amdgcn_mfma_f32_16x16x32_bf16(qh1, kl1, acc, 0, 0, 0);
      acc = __builtin_amdgcn_mfma_f32_16x16x32_bf16(qlo0, kh0, acc, 0, 0, 0);
      acc = __builtin_amdgcn_mfma_f32_16x16x32_bf16(qlo1, kh1, acc, 0, 0, 0);
      s[kf] = acc;
    }
    float alpha[4];
#pragma unroll
    for (int i = 0; i < 4; i++) {
      float mx = fmaxf(fmaxf(s[0][i], s[1][i]), fmaxf(s[2][i], s[3][i]));
      mx = fmaxf(mx, __shfl_xor(mx, 1));
      mx = fmaxf(mx, __shfl_xor(mx, 2));
      mx = fmaxf(mx, __shfl_xor(mx, 4));
      mx = fmaxf(mx, __shfl_xor(mx, 8));
      float mnew = fmaxf(mrow[i], mx);
      alpha[i] = __expf(mrow[i] - mnew);
      mrow[i] = mnew;
    }
    float rs[4] = {0.f, 0.f, 0.f, 0.f};
#pragma unroll
    for (int kf = 0; kf < 4; kf++) {
#pragma unroll
      for (int i = 0; i < 4; i++) {
        float p = __expf(s[kf][i] - mrow[i]);
        rs[i] += p;
        unsigned short hu, lu; splitf(p, hu, lu);
        int q = lg * 4 + i;
        PH[q * 72 + kf * 16 + lr] = hu;
        PL[q * 72 + kf * 16 + lr] = lu;
      }
    }
#pragma unroll
    for (int i = 0; i < 4; i++) {
      rs[i] += __shfl_xor(rs[i], 1);
      rs[i] += __shfl_xor(rs[i], 2);
      rs[i] += __shfl_xor(rs[i], 4);
      rs[i] += __shfl_xor(rs[i], 8);
      lsum[i] = lsum[i] * alpha[i] + rs[i];
    }
#pragma unroll
    for (int df = 0; df < 4; df++)
#pragma unroll
      for (int i = 0; i < 4; i++) O[df][i] *= alpha[i];

    int pbase = lr * 72 + lg * 8;
    short8v ph0 = *(const short8v*)&PH[pbase];
    short8v ph1 = *(const short8v*)&PH[pbase + 32];
    short8v pl0 = *(const short8v*)&PL[pbase];
    short8v pl1 = *(const short8v*)&PL[pbase + 32];
#pragma unroll
    for (int df = 0; df < 4; df++) {
      int vb = (df * 16 + lr) * 72 + lg * 8;
      short8v vh0 = *(const short8v*)&VtH[vb];
      short8v vh1 = *(const short8v*)&VtH[vb + 32];
      short8v vl0 = *(const short8v*)&VtL[vb];
      short8v vl1 = *(const short8v*)&VtL[vb + 32];
      f32x4 acc = O[df];
      acc = __builtin_amdgcn_mfma_f32_16x16x32_bf16(ph0, vh0, acc, 0, 0, 0);
      acc = __builtin_amdgcn_mfma_f32_16x16x32_bf16(ph1, vh1, acc, 0, 0, 0);
      acc = __builtin_amdgcn_mfma_f32_16x16x32_bf16(ph0, vl0, acc, 0, 0, 0);
      acc = __builtin_amdgcn_mfma_f32_16x16x32_bf16(ph1, vl1, acc, 0, 0, 0);
      acc = __builtin_amdgcn_mfma_f32_16x16x32_bf16(pl0, vh0, acc, 0, 0, 0);
      acc = __builtin_amdgcn_mfma_f32_16x16x32_bf16(pl1, vh1, acc, 0, 0, 0);
      O[df] = acc;
    }
    __syncthreads();
  }
#pragma unroll
  for (int i = 0; i < 4; i++) {
    float inv = 1.0f / lsum[i];
    int row = q0 + lg * 4 + i;
#pragma unroll
    for (int df = 0; df < 4; df++) {
      float v = O[df][i] * inv;
      unsigned short hu, lu; splitf(v, hu, lu);
      size_t off = hoff + (size_t)row * DIMD + df * 16 + lr;
      ATTh[off] = hu;
      ATTl[off] = lu;
    }
  }
}

// ---------------- FFN1: H[enc] = relu(OUT1[token]@W1c + b1) -> bf16 hi/lo ----------------
__global__ __launch_bounds__(256, 2) void ffn1_mfma(
    const unsigned short* __restrict__ Ah, const unsigned short* __restrict__ Al,
    const unsigned short* __restrict__ Bh, const unsigned short* __restrict__ Bl,
    const float* __restrict__ b1c,
    unsigned short* __restrict__ Hh, unsigned short* __restrict__ Hl,
    const int* __restrict__ lists, const int* __restrict__ counts) {
  int e = blockIdx.z;
  int cnt = counts[e];
  int m0 = blockIdx.x * 128;
  if (m0 >= cnt) return;
  __shared__ unsigned short lds[12288];
  __shared__ int rowenc[128];
  int t = threadIdx.x;
  if (t < 128) {
    int r = m0 + t;
    rowenc[t] = (r < cnt) ? lists[e * TTOK + r] : -1;
  }
  __syncthreads();
  int w = t >> 6, l = t & 63;
  int wr = w >> 1, wc = w & 1;
  int n0 = blockIdx.y * 64;
  f32x4 acc[4][2];
#pragma unroll
  for (int mf = 0; mf < 4; mf++)
#pragma unroll
    for (int nf = 0; nf < 2; nf++) acc[mf][nf] = {0.f, 0.f, 0.f, 0.f};
  int kb = (l >> 4) << 3;
  int enc0 = rowenc[(w * 2 + 0) * 16 + (l & 15)];
  int enc1 = rowenc[(w * 2 + 1) * 16 + (l & 15)];
  size_t rowoff0 = (size_t)(enc0 >= 0 ? (enc0 >> 1) : 0) * 512 + kb;
  size_t rowoff1 = (size_t)(enc1 >= 0 ? (enc1 >> 1) : 0) * 512 + kb;
  size_t bbase = (size_t)e * WPL + (size_t)(((n0 >> 4) + w) * 64 + l) * 8;
  mfma_loop(Ah, Al, rowoff0, rowoff1, Bh, Bl, bbase, lds, w, l, wr, wc, acc);
#pragma unroll
  for (int nf = 0; nf < 2; nf++) {
    int col = n0 + (wc * 2 + nf) * 16 + (l & 15);
    float bv = b1c[e * NFF + col];
#pragma unroll
    for (int mf = 0; mf < 4; mf++) {
      int lrow = (wr * 4 + mf) * 16 + ((l >> 4) << 2);
#pragma unroll
      for (int i = 0; i < 4; i++) {
        int enc = rowenc[lrow + i];
        if (enc >= 0) {
          float v = fmaxf(acc[mf][nf][i] + bv, 0.f);
          unsigned short hu, lu; splitf(v, hu, lu);
          Hh[(size_t)enc * 512 + col] = hu;
          Hl[(size_t)enc * 512 + col] = lu;
        }
      }
    }
  }
}

// ---------------- FFN2: Oslot[enc] (c==0? =bias+ : +=) H[enc] @ W2c ----------------
__global__ __launch_bounds__(256, 2) void ffn2_mfma(
    const unsigned short* __restrict__ Ah, const unsigned short* __restrict__ Al,
    const unsigned short* __restrict__ Bh, const unsigned short* __restrict__ Bl,
    const float* __restrict__ b2i,
    float* __restrict__ OS0, float* __restrict__ OS1,
    const int* __restrict__ lists, const int* __restrict__ counts, int c) {
  int e = blockIdx.z;
  int cnt = counts[e];
  int m0 = blockIdx.x * 128;
  if (m0 >= cnt) return;
  __shared__ unsigned short lds[12288];
  __shared__ int rowenc[128];
  int t = threadIdx.x;
  if (t < 128) {
    int r = m0 + t;
    rowenc[t] = (r < cnt) ? lists[e * TTOK + r] : -1;
  }
  __syncthreads();
  int w = t >> 6, l = t & 63;
  int wr = w >> 1, wc = w & 1;
  int n0 = blockIdx.y * 64;
  f32x4 acc[4][2];
#pragma unroll
  for (int mf = 0; mf < 4; mf++)
#pragma unroll
    for (int nf = 0; nf < 2; nf++) acc[mf][nf] = {0.f, 0.f, 0.f, 0.f};
  int kb = (l >> 4) << 3;
  int enc0 = rowenc[(w * 2 + 0) * 16 + (l & 15)];
  int enc1 = rowenc[(w * 2 + 1) * 16 + (l & 15)];
  size_t rowoff0 = (size_t)(enc0 >= 0 ? enc0 : 0) * 512 + kb;
  size_t rowoff1 = (size_t)(enc1 >= 0 ? enc1 : 0) * 512 + kb;
  size_t bbase = (size_t)e * WPL + (size_t)(((n0 >> 4) + w) * 64 + l) * 8;
  mfma_loop(Ah, Al, rowoff0, rowoff1, Bh, Bl, bbase, lds, w, l, wr, wc, acc);
#pragma unroll
  for (int nf = 0; nf < 2; nf++) {
    int col = n0 + (wc * 2 + nf) * 16 + (l & 15);
    float bv = b2i[e * DIMD + col];
#pragma unroll
    for (int mf = 0; mf < 4; mf++) {
      int lrow = (wr * 4 + mf) * 16 + ((l >> 4) << 2);
#pragma unroll
      for (int i = 0; i < 4; i++) {
        int enc = rowenc[lrow + i];
        if (enc >= 0) {
          float* dst = (enc < 8192 ? OS0 + (size_t)enc * 512
                                   : OS1 + (size_t)(enc - 8192) * 512) + col;
          float v = acc[mf][nf][i];
          if (c == 0) v += bv; else v += *dst;
          *dst = v;
        }
      }
    }
  }
}

// ---------------- LayerNorm((Xh+Xl) + p) * g + be -> bf16 hi/lo ----------------
__global__ __launch_bounds__(256) void ln_add_kernel(
    const unsigned short* __restrict__ Xh, const unsigned short* __restrict__ Xl,
    const float* __restrict__ p,
    const float* __restrict__ g, const float* __restrict__ be,
    unsigned short* __restrict__ outH, unsigned short* __restrict__ outL) {
  int wave = threadIdx.x >> 6;
  int lane = threadIdx.x & 63;
  int token = blockIdx.x * 4 + wave;
  short8v h8 = *(const short8v*)(Xh + (size_t)token * 512 + lane * 8);
  short8v l8 = *(const short8v*)(Xl + (size_t)token * 512 + lane * 8);
  const float* pr = p + (size_t)token * 512 + lane * 8;
  float pv[8];
  *(float4*)(&pv[0]) = *(const float4*)(pr);
  *(float4*)(&pv[4]) = *(const float4*)(pr + 4);
  float vals[8];
  float sum = 0.0f;
#pragma unroll
  for (int j = 0; j < 8; j++) {
    float v = bf2f((unsigned short)h8[j]) + bf2f((unsigned short)l8[j]) + pv[j];
    vals[j] = v; sum += v;
  }
#pragma unroll
  for (int off = 32; off; off >>= 1) sum += __shfl_xor(sum, off);
  float mu = sum * (1.0f / 512.0f);
  float sq = 0.0f;
#pragma unroll
  for (int j = 0; j < 8; j++) { vals[j] -= mu; sq += vals[j] * vals[j]; }
#pragma unroll
  for (int off = 32; off; off >>= 1) sq += __shfl_xor(sq, off);
  float rs = rsqrtf(sq * (1.0f / 512.0f) + 1e-6f);
  short8v oh, ol;
#pragma unroll
  for (int j = 0; j < 8; j++) {
    int d = lane * 8 + j;
    float y = vals[j] * rs * g[d] + be[d];
    unsigned short hu, lu; splitf(y, hu, lu);
    oh[j] = (short)hu; ol[j] = (short)lu;
  }
  *(short8v*)(outH + (size_t)token * 512 + lane * 8) = oh;
  *(short8v*)(outL + (size_t)token * 512 + lane * 8) = ol;
}

// ---------------- LayerNorm(OUT1 + g0*o0 + g1*o1) -> fp32 (last) or bf16 hi/lo ----------
__global__ __launch_bounds__(256) void ln_moe_kernel(
    const unsigned short* __restrict__ O1h, const unsigned short* __restrict__ O1l,
    const float* __restrict__ OS0, const float* __restrict__ OS1,
    const float* __restrict__ gates, const float* __restrict__ g,
    const float* __restrict__ be, float* __restrict__ outF,
    unsigned short* __restrict__ outH, unsigned short* __restrict__ outL) {
  int wave = threadIdx.x >> 6;
  int lane = threadIdx.x & 63;
  int token = blockIdx.x * 4 + wave;
  short8v h8 = *(const short8v*)(O1h + (size_t)token * 512 + lane * 8);
  short8v l8 = *(const short8v*)(O1l + (size_t)token * 512 + lane * 8);
  const float* ob = (token < 4096) ? (OS0 + (size_t)token * 1024)
                                   : (OS1 + ((size_t)token - 4096) * 1024);
  const float* o0 = ob + lane * 8;
  const float* o1 = ob + 512 + lane * 8;
  float gate0 = gates[token * 2], gate1 = gates[token * 2 + 1];
  float a0[8], a1[8];
  *(float4*)(&a0[0]) = *(const float4*)(o0);
  *(float4*)(&a0[4]) = *(const float4*)(o0 + 4);
  *(float4*)(&a1[0]) = *(const float4*)(o1);
  *(float4*)(&a1[4]) = *(const float4*)(o1 + 4);
  float vals[8];
  float sum = 0.0f;
#pragma unroll
  for (int j = 0; j < 8; j++) {
    float v = bf2f((unsigned short)h8[j]) + bf2f((unsigned short)l8[j]) +
              gate0 * a0[j] + gate1 * a1[j];
    vals[j] = v; sum += v;
  }
#pragma unroll
  for (int off = 32; off; off >>= 1) sum += __shfl_xor(sum, off);
  float mu = sum * (1.0f / 512.0f);
  float sq = 0.0f;
#pragma unroll
  for (int j = 0; j < 8; j++) { vals[j] -= mu; sq += vals[j] * vals[j]; }
#pragma unroll
  for (int off = 32; off; off >>= 1) sq += __shfl_xor(sq, off);
  float rs = rsqrtf(sq * (1.0f / 512.0f) + 1e-6f);
  if (outF) {
#pragma unroll
    for (int j = 0; j < 8; j++) {
      int d = lane * 8 + j;
      outF[(size_t)token * 512 + d] = vals[j] * rs * g[d] + be[d];
    }
  } else {
    short8v oh, ol;
#pragma unroll
    for (int j = 0; j < 8; j++) {
      int d = lane * 8 + j;
      float y = vals[j] * rs * g[d] + be[d];
      unsigned short hu, lu; splitf(y, hu, lu);
      oh[j] = (short)hu; ol[j] = (short)lu;
    }
    *(short8v*)(outH + (size_t)token * 512 + lane * 8) = oh;
    *(short8v*)(outL + (size_t)token * 512 + lane * 8) = ol;
  }
}

// ---------------- MoE routing: softmax top-2 + bucket by expert ----------------
__global__ __launch_bounds__(256) void route_kernel(
    const unsigned short* __restrict__ Xh, const unsigned short* __restrict__ Xl,
    const float* __restrict__ Wg, const float* __restrict__ bg,
    float* __restrict__ gates, int* __restrict__ lists, int* __restrict__ counts) {
  int wave = threadIdx.x >> 6;
  int lane = threadIdx.x & 63;
  int token = blockIdx.x * 4 + wave;
  float acc[8];
#pragma unroll
  for (int e = 0; e < 8; e++) acc[e] = 0.0f;
  for (int it = 0; it < 8; it++) {
    int d = it * 64 + lane;
    float xv = bf2f(Xh[(size_t)token * 512 + d]) + bf2f(Xl[(size_t)token * 512 + d]);
    float4 w0 = *(const float4*)(Wg + d * 8);
    float4 w1 = *(const float4*)(Wg + d * 8 + 4);
    acc[0] += xv * w0.x; acc[1] += xv * w0.y;
    acc[2] += xv * w0.z; acc[3] += xv * w0.w;
    acc[4] += xv * w1.x; acc[5] += xv * w1.y;
    acc[6] += xv * w1.z; acc[7] += xv * w1.w;
  }
#pragma unroll
  for (int e = 0; e < 8; e++)
#pragma unroll
    for (int off = 32; off; off >>= 1) acc[e] += __shfl_xor(acc[e], off);
  if (lane == 0) {
    float lg[8];
    float mx = -1e30f;
#pragma unroll
    for (int e = 0; e < 8; e++) { lg[e] = acc[e] + bg[e]; mx = fmaxf(mx, lg[e]); }
#pragma unroll
    for (int e = 0; e < 8; e++) lg[e] = __expf(lg[e] - mx);
    int i0 = 0; float v0 = lg[0];
#pragma unroll
    for (int e = 1; e < 8; e++) if (lg[e] > v0) { v0 = lg[e]; i0 = e; }
    int i1 = -1; float v1 = -1.0f;
#pragma unroll
    for (int e = 0; e < 8; e++)
      if (e != i0 && lg[e] > v1) { v1 = lg[e]; i1 = e; }
    float inv = 1.0f / (v0 + v1);
    gates[token * 2] = v0 * inv;
    gates[token * 2 + 1] = v1 * inv;
    int p0 = atomicAdd(&counts[i0], 1);
    lists[i0 * TTOK + p0] = token * 2;
    int p1 = atomicAdd(&counts[i1], 1);
    lists[i1 * TTOK + p1] = token * 2 + 1;
  }
}

__global__ void zero_counts_kernel(int* counts) {
  if (threadIdx.x < NEXP) counts[threadIdx.x] = 0;
}

// ---------------- host orchestration ----------------
// Workspace (aliased by phase; ~100.4 MB):
//  [0..16M)    Xh(8M)+Xl(8M)              | Hl (MoE)
//  [16..32M)   Qh(8M)+Ql(8M)              | W1c/W2c images (4 x 4M)
//  [32..48M)   Kh(8M)+Kl(8M)              | PROJ fp32 | OS0
//  [48..64M)   Vh(8M)+Vl(8M)              | OUT1h+OUT1l
//  [64..80M)   ATTh(8M)+ATTl(8M)          | Hh (MoE)
//  [80..84M)   Wq/Wk/Wv/Wo images (8 planes)
//  [84..100M)  OS1
//  [100M..)    GATES LISTS COUNTS
extern "C" void kernel_launch(void* const* d_in, const int* in_sizes, int n_in,
                              void* d_out, int out_size, void* d_ws, size_t ws_size,
                              hipStream_t stream) {
  (void)in_sizes; (void)n_in; (void)out_size; (void)ws_size;
  const int*   tokens = (const int*)d_in[0];
  const float* emb = (const float*)d_in[1];
  const float* Wq = (const float*)d_in[2];
  const float* bq = (const float*)d_in[3];
  const float* Wk = (const float*)d_in[4];
  const float* bk = (const float*)d_in[5];
  const float* Wv = (const float*)d_in[6];
  const float* bv = (const float*)d_in[7];
  const float* Wo = (const float*)d_in[8];
  const float* bo = (const float*)d_in[9];
  const float* Wg = (const float*)d_in[10];
  const float* bg = (const float*)d_in[11];
  const float* W1 = (const float*)d_in[12];
  const float* b1 = (const float*)d_in[13];
  const float* W2 = (const float*)d_in[14];
  const float* b2 = (const float*)d_in[15];
  const float* g1 = (const float*)d_in[16];
  const float* be1 = (const float*)d_in[17];
  const float* g2 = (const float*)d_in[18];
  const float* be2 = (const float*)d_in[19];

  char* base = (char*)d_ws;
  const size_t MB = 1024u * 1024u;
  unsigned short* Xh   = (unsigned short*)(base + 0 * MB);
  unsigned short* Xl   = (unsigned short*)(base + 8 * MB);
  unsigned short* Hl   = (unsigned short*)(base + 0 * MB);
  unsigned short* Qh   = (unsigned short*)(base + 16 * MB);
  unsigned short* Ql   = (unsigned short*)(base + 24 * MB);
  unsigned short* W1h  = (unsigned short*)(base + 16 * MB);
  unsigned short* W1l  = (unsigned short*)(base + 20 * MB);
  unsigned short* W2h  = (unsigned short*)(base + 24 * MB);
  unsigned short* W2l  = (unsigned short*)(base + 28 * MB);
  unsigned short* Kh   = (unsigned short*)(base + 32 * MB);
  unsigned short* Kl   = (unsigned short*)(base + 40 * MB);
  float*          PROJ = (float*)(base + 32 * MB);
  float*          OS0  = (float*)(base + 32 * MB);
  unsigned short* Vh   = (unsigned short*)(base + 48 * MB);
  unsigned short* Vl   = (unsigned short*)(base + 56 * MB);
  unsigned short* O1h  = (unsigned short*)(base + 48 * MB);
  unsigned short* O1l  = (unsigned short*)(base + 56 * MB);
  unsigned short* ATTh = (unsigned short*)(base + 64 * MB);
  unsigned short* ATTl = (unsigned short*)(base + 72 * MB);
  unsigned short* Hh   = (unsigned short*)(base + 64 * MB);
  unsigned short* Wimg = (unsigned short*)(base + 80 * MB);
  float*          OS1  = (float*)(base + 84 * MB);
  float*          GATES = (float*)(base + 100 * MB);
  int*            LISTS = (int*)(base + 100 * MB + 65536);
  int*            COUNTS = (int*)(base + 100 * MB + 65536 + 262144);

  dim3 blk(256);
  embed_kernel<<<(TTOK * DIMD) / 256, blk, 0, stream>>>(tokens, emb, Xh, Xl);

  for (int i = 0; i < NLAYER; i++) {
    const float* wq = Wq + (size_t)i * DIMD * DIMD;
    const float* wk = Wk + (size_t)i * DIMD * DIMD;
    const float* wv = Wv + (size_t)i * DIMD * DIMD;
    const float* wo = Wo + (size_t)i * DIMD * DIMD;
    const float* bqi = bq + (size_t)i * DIMD;
    const float* bki = bk + (size_t)i * DIMD;
    const float* bvi = bv + (size_t)i * DIMD;
    const float* boi = bo + (size_t)i * DIMD;
    const float* wgi = Wg + (size_t)i * DIMD * NEXP;
    const float* bgi = bg + (size_t)i * NEXP;
    const float* w1i = W1 + (size_t)i * NEXP * DIMD * NFF;
    const float* b1i = b1 + (size_t)i * NEXP * NFF;
    const float* w2i = W2 + (size_t)i * NEXP * NFF * DIMD;
    const float* b2i = b2 + (size_t)i * NEXP * DIMD;
    const float* g1i = g1 + (size_t)i * DIMD;
    const float* be1i = be1 + (size_t)i * DIMD;
    const float* g2i = g2 + (size_t)i * DIMD;
    const float* be2i = be2 + (size_t)i * DIMD;

    // one dispatch converts Wq/Wk/Wv/Wo into fragment images (planes 0..7)
    conv_qkvo_kernel<<<dim3(128, 4), blk, 0, stream>>>(wq, wk, wv, wo, Wimg);

    // fused Q/K/V GEMM (z in {0,1,2}) then attention then proj
    gemm_qkv<<<dim3(64, 8, 3), blk, 0, stream>>>(
        Xh, Xl, Wimg, bqi, bki, bvi, Qh, Ql, Kh, Kl, Vh, Vl);
    attn_mfma<<<dim3(SEQ / 64, 32), blk, 0, stream>>>(Qh, Ql, Kh, Kl, Vh, Vl, ATTh, ATTl);
    gemm_dense<<<dim3(64, 8), blk, 0, stream>>>(
        ATTh, ATTl, Wimg + 6 * (size_t)WPL, Wimg + 7 * (size_t)WPL, boi, PROJ);

    ln_add_kernel<<<TTOK / 4, blk, 0, stream>>>(Xh, Xl, PROJ, g1i, be1i, O1h, O1l);
    zero_counts_kernel<<<1, 64, 0, stream>>>(COUNTS);
    route_kernel<<<TTOK / 4, blk, 0, stream>>>(O1h, O1l, wgi, bgi, GATES, LISTS, COUNTS);

    for (int c = 0; c < 4; c++) {
      conv_w12_kernel<<<dim3(128, 2, 8), blk, 0, stream>>>(
          w1i + c * 512, w2i + (size_t)c * 512 * DIMD, W1h, W1l, W2h, W2l);
      ffn1_mfma<<<dim3(64, 8, 8), blk, 0, stream>>>(
          O1h, O1l, W1h, W1l, b1i + c * 512, Hh, Hl, LISTS, COUNTS);
      ffn2_mfma<<<dim3(64, 8, 8), blk, 0, stream>>>(
          Hh, Hl, W2h, W2l, b2i, OS0, OS1, LISTS, COUNTS, c);
    }
    float* xout = (i == NLAYER - 1) ? (float*)d_out : nullptr;
    ln_moe_kernel<<<TTOK / 4, blk, 0, stream>>>(
        O1h, O1l, OS0, OS1, GATES, g2i, be2i, xout, Xh, Xl);
  }
}